// Round 2
// baseline (164.957 us; speedup 1.0000x reference)
//
#include <hip/hip_runtime.h>

typedef _Float16 h16;
typedef __attribute__((ext_vector_type(8))) _Float16 f16x8;
typedef __attribute__((ext_vector_type(4))) float f32x4;

#define TOKENS 2048
#define INF    4096   // n_codes * 8
#define OUTF   4096   // m
#define GK     4096

// ---------------------------------------------------------------------------
// Kernel 1: decompress E8P codes -> W (4096 x 4096 fp16, row-major, K-contig)
// Robust to grid_abs arriving as f16 (expected), f32, or bf16: first grid row
// is all 0.5 -> first u16 is 0x3800 (f16) / 0x0000 (f32 low half) / 0x3F00 (bf16).
// ---------------------------------------------------------------------------
__global__ __launch_bounds__(256) void k_decompress(const int* __restrict__ Q,
                                                    const void* __restrict__ gridraw,
                                                    h16* __restrict__ W) {
    __shared__ float gT[8][256];   // transposed LUT: gather bank = absIdx%32
    __shared__ int   gOdd[256];
    const int tid = threadIdx.x;

    const unsigned short* gu = (const unsigned short*)gridraw;
    const float*          gf = (const float*)gridraw;
    const unsigned short  p0 = gu[0];

    float sum = 0.f;
#pragma unroll
    for (int j = 0; j < 8; ++j) {
        float v;
        if (p0 == 0x3800) {                       // float16
            unsigned short u = gu[tid * 8 + j];
            h16 hv; __builtin_memcpy(&hv, &u, 2);
            v = (float)hv;
        } else if (p0 == 0x3F00) {                // bfloat16
            unsigned int u = ((unsigned int)gu[tid * 8 + j]) << 16;
            __builtin_memcpy(&v, &u, 4);
        } else {                                  // float32
            v = gf[tid * 8 + j];
        }
        gT[j][tid] = v;
        sum += v;
    }
    gOdd[tid] = ((int)(sum + 0.5f)) & 1;          // abs_odd = round(sum)%2
    __syncthreads();

    const int code = blockIdx.x * 256 + tid;      // 4096*512 codes total
    const int q        = Q[code];
    const int absIdx   = (q >> 8) & 255;
    const int signBits = (q >> 1) & 127;
    const float shift  = (q & 1) ? 0.25f : -0.25f;
    const int neg0 = (__popc(signBits) ^ gOdd[absIdx]) & 1;

    f16x8 o;
    o[0] = (h16)(gT[0][absIdx] * (1.0f - 2.0f * (float)neg0) + shift);
#pragma unroll
    for (int i = 1; i < 8; ++i) {
        float sg = 1.0f - 2.0f * (float)((signBits >> (i - 1)) & 1);
        o[i] = (h16)(gT[i][absIdx] * sg + shift);
    }
    *reinterpret_cast<f16x8*>(W + (size_t)code * 8) = o;
}

// ---------------------------------------------------------------------------
// FWHT-4096 in LDS, 12 stages, 256 threads, 8 butterflies/thread/stage
// ---------------------------------------------------------------------------
__device__ __forceinline__ void fwht4096(float* s, int tid) {
#pragma unroll
    for (int c = 1; c < 4096; c <<= 1) {
        __syncthreads();
#pragma unroll
        for (int r = 0; r < 8; ++r) {
            int idx = tid + r * 256;          // 0..2047
            int j   = idx & (c - 1);
            int i0  = ((idx - j) << 1) + j;
            float a = s[i0], b = s[i0 + c];
            s[i0]     = a + b;
            s[i0 + c] = a - b;
        }
    }
    __syncthreads();
}

// ---------------------------------------------------------------------------
// Kernel 2: y = fp16( FWHT(x * SU) / 64 )
// ---------------------------------------------------------------------------
__global__ __launch_bounds__(256) void k_fwht_in(const float* __restrict__ X,
                                                 const float* __restrict__ SU,
                                                 h16* __restrict__ Y) {
    __shared__ float s[4096];
    const int row = blockIdx.x, tid = threadIdx.x;
    const float4* x4  = reinterpret_cast<const float4*>(X + (size_t)row * INF);
    const float4* su4 = reinterpret_cast<const float4*>(SU);
    float4* s4 = reinterpret_cast<float4*>(s);
#pragma unroll
    for (int r = 0; r < 4; ++r) {
        int i = tid + r * 256;
        float4 v = x4[i], u = su4[i];
        float4 o; o.x = v.x*u.x; o.y = v.y*u.y; o.z = v.z*u.z; o.w = v.w*u.w;
        s4[i] = o;
    }
    fwht4096(s, tid);
#pragma unroll
    for (int r = 0; r < 2; ++r) {
        int i = tid + r * 256;
        f16x8 o;
#pragma unroll
        for (int j = 0; j < 8; ++j) o[j] = (h16)(s[i * 8 + j] * 0.015625f);
        *reinterpret_cast<f16x8*>(Y + (size_t)row * INF + i * 8) = o;
    }
}

// ---------------------------------------------------------------------------
// Kernel 3: GEMM  z[t][j] = sum_k y[t][k] * W[j][k]   (NT, both K-major)
// 128x128 tile, BK=64, 4 waves (2x2 of 64x64), mfma_f32_16x16x32_f16.
// Register-staged LDS (ds_write_b128), XOR swizzle applied symmetrically on
// the write AND read side (chunk ^= row&7). XCD-aware block swizzle.
// ---------------------------------------------------------------------------
#define BM 128
#define BN 128
#define BK 64

__global__ __launch_bounds__(256) void k_gemm(const h16* __restrict__ A,
                                              const h16* __restrict__ B,
                                              float* __restrict__ C) {
    __shared__ __align__(16) h16 lA[BM * BK];
    __shared__ __align__(16) h16 lB[BN * BK];
    const int tid  = threadIdx.x;
    const int lane = tid & 63;

    // grid = 512 = 16 mT x 32 nT ; 512 % 8 == 0 -> bijective XCD swizzle
    const int bid = blockIdx.x;
    const int swz = (bid & 7) * 64 + (bid >> 3);
    const int mT  = swz & 15;
    const int nT  = swz >> 4;
    const int w   = tid >> 6;
    const int wr  = w >> 1, wc = w & 1;

    // staging: 1024 16B-chunks per tile; thread handles ch = it*256 + tid
    size_t aOff[4], bOff[4];
    int ldsOff[4];
#pragma unroll
    for (int it = 0; it < 4; ++it) {
        int ch = it * 256 + tid;
        int rr = ch >> 3, cc = ch & 7;
        aOff[it] = (size_t)(mT * BM + rr) * GK + cc * 8;
        bOff[it] = (size_t)(nT * BN + rr) * GK + cc * 8;
        ldsOff[it] = (rr * 8 + (cc ^ (rr & 7))) * 8;   // swizzled LDS chunk
    }

    f32x4 acc[4][4] = {};
    const int laneRow = lane & 15;
    const int laneK   = lane >> 4;   // 0..3

    for (int k0 = 0; k0 < GK; k0 += BK) {
        f16x8 ar[4], br[4];
#pragma unroll
        for (int it = 0; it < 4; ++it)
            ar[it] = *reinterpret_cast<const f16x8*>(A + aOff[it] + k0);
#pragma unroll
        for (int it = 0; it < 4; ++it)
            br[it] = *reinterpret_cast<const f16x8*>(B + bOff[it] + k0);

        __syncthreads();   // previous iteration's LDS reads complete
#pragma unroll
        for (int it = 0; it < 4; ++it)
            *reinterpret_cast<f16x8*>(lA + ldsOff[it]) = ar[it];
#pragma unroll
        for (int it = 0; it < 4; ++it)
            *reinterpret_cast<f16x8*>(lB + ldsOff[it]) = br[it];
        __syncthreads();   // tile visible to all waves

#pragma unroll
        for (int kk = 0; kk < 2; ++kk) {
            const int cBase = kk * 4 + laneK;   // 16B chunk index in row
            f16x8 af[4], bf[4];
#pragma unroll
            for (int mi = 0; mi < 4; ++mi) {
                int r = wr * 64 + mi * 16 + laneRow;
                af[mi] = *reinterpret_cast<const f16x8*>(lA + (r * 8 + (cBase ^ (r & 7))) * 8);
            }
#pragma unroll
            for (int nj = 0; nj < 4; ++nj) {
                int r = wc * 64 + nj * 16 + laneRow;
                bf[nj] = *reinterpret_cast<const f16x8*>(lB + (r * 8 + (cBase ^ (r & 7))) * 8);
            }
#pragma unroll
            for (int mi = 0; mi < 4; ++mi)
#pragma unroll
                for (int nj = 0; nj < 4; ++nj)
                    acc[mi][nj] = __builtin_amdgcn_mfma_f32_16x16x32_f16(
                        af[mi], bf[nj], acc[mi][nj], 0, 0, 0);
        }
    }

    // C/D layout: col = lane&15, row = (lane>>4)*4 + reg   [guide m89]
    const int col0 = nT * BN + wc * 64 + laneRow;
    const int row0 = mT * BM + wr * 64 + laneK * 4;
#pragma unroll
    for (int mi = 0; mi < 4; ++mi)
#pragma unroll
        for (int nj = 0; nj < 4; ++nj)
#pragma unroll
            for (int rg = 0; rg < 4; ++rg)
                C[(size_t)(row0 + mi * 16 + rg) * OUTF + col0 + nj * 16] = acc[mi][nj][rg];
}

// ---------------------------------------------------------------------------
// Kernel 4: out = FWHT(z) * (Wscale/64) * SV   (in-place on d_out)
// ---------------------------------------------------------------------------
__global__ __launch_bounds__(256) void k_fwht_out(float* __restrict__ Z,
                                                  const float* __restrict__ SV,
                                                  const float* __restrict__ wscale) {
    __shared__ float s[4096];
    const int row = blockIdx.x, tid = threadIdx.x;
    float4* z4 = reinterpret_cast<float4*>(Z + (size_t)row * OUTF);
    float4* s4 = reinterpret_cast<float4*>(s);
#pragma unroll
    for (int r = 0; r < 4; ++r) { int i = tid + r * 256; s4[i] = z4[i]; }
    fwht4096(s, tid);
    const float sc = wscale[0] * 0.015625f;
    const float4* sv4 = reinterpret_cast<const float4*>(SV);
#pragma unroll
    for (int r = 0; r < 4; ++r) {
        int i = tid + r * 256;
        float4 u = sv4[i];
        float4 v;
        v.x = s[i*4+0] * sc * u.x;
        v.y = s[i*4+1] * sc * u.y;
        v.z = s[i*4+2] * sc * u.z;
        v.w = s[i*4+3] * sc * u.w;
        z4[i] = v;
    }
}

// ---------------------------------------------------------------------------
extern "C" void kernel_launch(void* const* d_in, const int* in_sizes, int n_in,
                              void* d_out, int out_size, void* d_ws, size_t ws_size,
                              hipStream_t stream) {
    const float* input  = (const float*)d_in[0];   // (2048, 4096) f32
    const int*   Qidxs  = (const int*)d_in[1];     // (4096, 512) i32
    const float* SU     = (const float*)d_in[2];   // (4096,) f32
    const float* SV     = (const float*)d_in[3];   // (4096,) f32
    const float* Wscale = (const float*)d_in[4];   // (1,) f32
    const void*  grid   = (const void*)d_in[9];    // (256, 8) f16 (dtype-probed)

    h16*   W = (h16*)d_ws;                                        // 32 MB
    h16*   Y = (h16*)((char*)d_ws + (size_t)OUTF * GK * 2);       // 16 MB
    float* Z = (float*)d_out;                                     // 32 MB

    hipLaunchKernelGGL(k_decompress, dim3((OUTF * 512) / 256), dim3(256), 0, stream,
                       Qidxs, grid, W);
    hipLaunchKernelGGL(k_fwht_in, dim3(TOKENS), dim3(256), 0, stream,
                       input, SU, Y);
    hipLaunchKernelGGL(k_gemm, dim3((TOKENS / BM) * (OUTF / BN)), dim3(256), 0, stream,
                       Y, W, Z);
    hipLaunchKernelGGL(k_fwht_out, dim3(TOKENS), dim3(256), 0, stream,
                       Z, SV, Wscale);
}

// Round 3
// 145.002 us; speedup vs baseline: 1.1376x; 1.1376x over previous
//
#include <hip/hip_runtime.h>

typedef _Float16 h16;
typedef __attribute__((ext_vector_type(8))) _Float16 f16x8;
typedef __attribute__((ext_vector_type(4))) float f32x4;

#define TOKENS 2048
#define INF    4096   // n_codes * 8
#define OUTF   4096   // m
#define GK     4096

// ---------------------------------------------------------------------------
// Kernel 1: decompress E8P codes -> W (4096 x 4096 fp16, row-major, K-contig)
// (unchanged from passing round-2 version)
// ---------------------------------------------------------------------------
__global__ __launch_bounds__(256) void k_decompress(const int* __restrict__ Q,
                                                    const void* __restrict__ gridraw,
                                                    h16* __restrict__ W) {
    __shared__ float gT[8][256];   // transposed LUT: gather bank = absIdx%32
    __shared__ int   gOdd[256];
    const int tid = threadIdx.x;

    const unsigned short* gu = (const unsigned short*)gridraw;
    const float*          gf = (const float*)gridraw;
    const unsigned short  p0 = gu[0];

    float sum = 0.f;
#pragma unroll
    for (int j = 0; j < 8; ++j) {
        float v;
        if (p0 == 0x3800) {                       // float16
            unsigned short u = gu[tid * 8 + j];
            h16 hv; __builtin_memcpy(&hv, &u, 2);
            v = (float)hv;
        } else if (p0 == 0x3F00) {                // bfloat16
            unsigned int u = ((unsigned int)gu[tid * 8 + j]) << 16;
            __builtin_memcpy(&v, &u, 4);
        } else {                                  // float32
            v = gf[tid * 8 + j];
        }
        gT[j][tid] = v;
        sum += v;
    }
    gOdd[tid] = ((int)(sum + 0.5f)) & 1;          // abs_odd = round(sum)%2
    __syncthreads();

    const int code = blockIdx.x * 256 + tid;      // 4096*512 codes total
    const int q        = Q[code];
    const int absIdx   = (q >> 8) & 255;
    const int signBits = (q >> 1) & 127;
    const float shift  = (q & 1) ? 0.25f : -0.25f;
    const int neg0 = (__popc(signBits) ^ gOdd[absIdx]) & 1;

    f16x8 o;
    o[0] = (h16)(gT[0][absIdx] * (1.0f - 2.0f * (float)neg0) + shift);
#pragma unroll
    for (int i = 1; i < 8; ++i) {
        float sg = 1.0f - 2.0f * (float)((signBits >> (i - 1)) & 1);
        o[i] = (h16)(gT[i][absIdx] * sg + shift);
    }
    *reinterpret_cast<f16x8*>(W + (size_t)code * 8) = o;
}

// ---------------------------------------------------------------------------
// FWHT-16 fully in registers (static indices -> stays in VGPRs, rule #20)
// ---------------------------------------------------------------------------
__device__ __forceinline__ void fwht16(float v[16]) {
#pragma unroll
    for (int s = 1; s < 16; s <<= 1)
#pragma unroll
        for (int j = 0; j < 16; ++j)
            if (!(j & s)) {
                float a = v[j], b = v[j + s];
                v[j]     = a + b;
                v[j + s] = a - b;
            }
}

// FWHT-4096 = H16 (digit a, stride 256) x H16 (digit b, stride 16) x H16 (c, stride 1)
// LDS padded: phys(i) = i + (i>>4); all passes <=2-way bank aliasing.
#define PHYS(i) ((i) + ((i) >> 4))

// ---------------------------------------------------------------------------
// Kernel 2: y = fp16( FWHT(x * SU) / 64 )   — radix-16^3
// ---------------------------------------------------------------------------
__global__ __launch_bounds__(256) void k_fwht_in(const float* __restrict__ X,
                                                 const float* __restrict__ SU,
                                                 h16* __restrict__ Y) {
    __shared__ float s[4096 + 256];
    const int row = blockIdx.x, t = threadIdx.x;
    const int hi = t >> 4, lo = t & 15;
    float v[16];
    const float* xr = X + (size_t)row * INF;

    // pass A: digit a; thread owns (b,c)=(hi,lo); element j*256 + t
#pragma unroll
    for (int j = 0; j < 16; ++j) v[j] = xr[j * 256 + t] * SU[j * 256 + t];
    fwht16(v);
#pragma unroll
    for (int j = 0; j < 16; ++j) s[272 * j + 17 * hi + lo] = v[j];  // PHYS(j*256+hi*16+lo)
    __syncthreads();

    // pass B: digit b; thread owns (a,c)=(hi,lo)
#pragma unroll
    for (int j = 0; j < 16; ++j) v[j] = s[272 * hi + 17 * j + lo];
    fwht16(v);
#pragma unroll
    for (int j = 0; j < 16; ++j) s[272 * hi + 17 * j + lo] = v[j];
    __syncthreads();

    // pass C: digit c; thread owns (a,b)=(hi,lo); phys contiguous 16-run
    const int base = 272 * hi + 17 * lo;
#pragma unroll
    for (int j = 0; j < 16; ++j) v[j] = s[base + j];
    fwht16(v);

    // output element index = hi*256 + lo*16 + j = t*16 + j  (32B/lane, coalesced)
    f16x8 o0, o1;
#pragma unroll
    for (int j = 0; j < 8; ++j) {
        o0[j] = (h16)(v[j]     * 0.015625f);
        o1[j] = (h16)(v[j + 8] * 0.015625f);
    }
    f16x8* out = reinterpret_cast<f16x8*>(Y + (size_t)row * INF + t * 16);
    out[0] = o0; out[1] = o1;
}

// ---------------------------------------------------------------------------
// Kernel 3: GEMM  z[t][j] = sum_k y[t][k] * W[j][k]   (NT, both K-major)
// 128x128 tile, BK=64, 4 waves (2x2 of 64x64), mfma_f32_16x16x32_f16.
// Double-buffered LDS, ONE barrier per K-step, next-tile loads issued before
// compute (latency hidden under MFMA). XOR swizzle write+read. XCD swizzle.
// ---------------------------------------------------------------------------
#define BM 128
#define BN 128
#define BK 64
#define NSTEP (GK / BK)   // 64

__global__ __launch_bounds__(256) void k_gemm(const h16* __restrict__ A,
                                              const h16* __restrict__ B,
                                              float* __restrict__ C) {
    __shared__ __align__(16) h16 lA[2][BM * BK];
    __shared__ __align__(16) h16 lB[2][BN * BK];
    const int tid  = threadIdx.x;
    const int lane = tid & 63;

    // grid = 512 = 16 mT x 32 nT ; 512 % 8 == 0 -> bijective XCD swizzle
    const int bid = blockIdx.x;
    const int swz = (bid & 7) * 64 + (bid >> 3);
    const int mT  = swz & 15;
    const int nT  = swz >> 4;
    const int w   = tid >> 6;
    const int wr  = w >> 1, wc = w & 1;

    size_t aOff[4], bOff[4];
    int ldsOff[4];
#pragma unroll
    for (int it = 0; it < 4; ++it) {
        int ch = it * 256 + tid;
        int rr = ch >> 3, cc = ch & 7;
        aOff[it] = (size_t)(mT * BM + rr) * GK + cc * 8;
        bOff[it] = (size_t)(nT * BN + rr) * GK + cc * 8;
        ldsOff[it] = (rr * 8 + (cc ^ (rr & 7))) * 8;   // swizzled LDS chunk
    }

    f32x4 acc[4][4] = {};
    const int laneRow = lane & 15;
    const int laneK   = lane >> 4;   // 0..3

    f16x8 ar[4], br[4];
    // prologue: stage tile 0 into buf 0
#pragma unroll
    for (int it = 0; it < 4; ++it) ar[it] = *reinterpret_cast<const f16x8*>(A + aOff[it]);
#pragma unroll
    for (int it = 0; it < 4; ++it) br[it] = *reinterpret_cast<const f16x8*>(B + bOff[it]);
#pragma unroll
    for (int it = 0; it < 4; ++it) *reinterpret_cast<f16x8*>(&lA[0][0] + ldsOff[it]) = ar[it];
#pragma unroll
    for (int it = 0; it < 4; ++it) *reinterpret_cast<f16x8*>(&lB[0][0] + ldsOff[it]) = br[it];
    __syncthreads();

    int cur = 0;
    for (int t = 0; t < NSTEP - 1; ++t) {
        const int k0 = (t + 1) * BK;
        // issue next tile's global loads FIRST (hide latency under MFMA)
#pragma unroll
        for (int it = 0; it < 4; ++it) ar[it] = *reinterpret_cast<const f16x8*>(A + aOff[it] + k0);
#pragma unroll
        for (int it = 0; it < 4; ++it) br[it] = *reinterpret_cast<const f16x8*>(B + bOff[it] + k0);

        const h16* pA = &lA[cur][0];
        const h16* pB = &lB[cur][0];
#pragma unroll
        for (int kk = 0; kk < 2; ++kk) {
            const int cBase = kk * 4 + laneK;   // 16B chunk index in row
            f16x8 af[4], bf[4];
#pragma unroll
            for (int mi = 0; mi < 4; ++mi) {
                int r = wr * 64 + mi * 16 + laneRow;
                af[mi] = *reinterpret_cast<const f16x8*>(pA + (r * 8 + (cBase ^ (r & 7))) * 8);
            }
#pragma unroll
            for (int nj = 0; nj < 4; ++nj) {
                int r = wc * 64 + nj * 16 + laneRow;
                bf[nj] = *reinterpret_cast<const f16x8*>(pB + (r * 8 + (cBase ^ (r & 7))) * 8);
            }
#pragma unroll
            for (int mi = 0; mi < 4; ++mi)
#pragma unroll
                for (int nj = 0; nj < 4; ++nj)
                    acc[mi][nj] = __builtin_amdgcn_mfma_f32_16x16x32_f16(
                        af[mi], bf[nj], acc[mi][nj], 0, 0, 0);
        }

        // write next tile into the OTHER buffer (no conflict with readers of cur)
        h16* qA = &lA[cur ^ 1][0];
        h16* qB = &lB[cur ^ 1][0];
#pragma unroll
        for (int it = 0; it < 4; ++it) *reinterpret_cast<f16x8*>(qA + ldsOff[it]) = ar[it];
#pragma unroll
        for (int it = 0; it < 4; ++it) *reinterpret_cast<f16x8*>(qB + ldsOff[it]) = br[it];
        __syncthreads();
        cur ^= 1;
    }

    // final tile compute (no prefetch)
    {
        const h16* pA = &lA[cur][0];
        const h16* pB = &lB[cur][0];
#pragma unroll
        for (int kk = 0; kk < 2; ++kk) {
            const int cBase = kk * 4 + laneK;
            f16x8 af[4], bf[4];
#pragma unroll
            for (int mi = 0; mi < 4; ++mi) {
                int r = wr * 64 + mi * 16 + laneRow;
                af[mi] = *reinterpret_cast<const f16x8*>(pA + (r * 8 + (cBase ^ (r & 7))) * 8);
            }
#pragma unroll
            for (int nj = 0; nj < 4; ++nj) {
                int r = wc * 64 + nj * 16 + laneRow;
                bf[nj] = *reinterpret_cast<const f16x8*>(pB + (r * 8 + (cBase ^ (r & 7))) * 8);
            }
#pragma unroll
            for (int mi = 0; mi < 4; ++mi)
#pragma unroll
                for (int nj = 0; nj < 4; ++nj)
                    acc[mi][nj] = __builtin_amdgcn_mfma_f32_16x16x32_f16(
                        af[mi], bf[nj], acc[mi][nj], 0, 0, 0);
        }
    }

    // C/D layout: col = lane&15, row = (lane>>4)*4 + reg   [guide m89]
    const int col0 = nT * BN + wc * 64 + laneRow;
    const int row0 = mT * BM + wr * 64 + laneK * 4;
#pragma unroll
    for (int mi = 0; mi < 4; ++mi)
#pragma unroll
        for (int nj = 0; nj < 4; ++nj)
#pragma unroll
            for (int rg = 0; rg < 4; ++rg)
                C[(size_t)(row0 + mi * 16 + rg) * OUTF + col0 + nj * 16] = acc[mi][nj][rg];
}

// ---------------------------------------------------------------------------
// Kernel 4: out = FWHT(z) * (Wscale/64) * SV   — radix-16^3, in-place on d_out
// ---------------------------------------------------------------------------
__global__ __launch_bounds__(256) void k_fwht_out(float* __restrict__ Z,
                                                  const float* __restrict__ SV,
                                                  const float* __restrict__ wscale) {
    __shared__ float s[4096 + 256];
    const int row = blockIdx.x, t = threadIdx.x;
    const int hi = t >> 4, lo = t & 15;
    float v[16];
    float* zr = Z + (size_t)row * OUTF;

    // pass A: digit a
#pragma unroll
    for (int j = 0; j < 16; ++j) v[j] = zr[j * 256 + t];
    fwht16(v);
#pragma unroll
    for (int j = 0; j < 16; ++j) s[272 * j + 17 * hi + lo] = v[j];
    __syncthreads();

    // pass B: digit b
#pragma unroll
    for (int j = 0; j < 16; ++j) v[j] = s[272 * hi + 17 * j + lo];
    fwht16(v);
#pragma unroll
    for (int j = 0; j < 16; ++j) s[272 * hi + 17 * j + lo] = v[j];
    __syncthreads();

    // pass C: digit c (contiguous phys)
    const int base = 272 * hi + 17 * lo;
#pragma unroll
    for (int j = 0; j < 16; ++j) v[j] = s[base + j];
    fwht16(v);

    const float sc = wscale[0] * 0.015625f;
    const float4* sv4 = reinterpret_cast<const float4*>(SV + t * 16);
    float4* z4 = reinterpret_cast<float4*>(zr + t * 16);
#pragma unroll
    for (int q = 0; q < 4; ++q) {
        float4 u = sv4[q];
        float4 o;
        o.x = v[q*4+0] * sc * u.x;
        o.y = v[q*4+1] * sc * u.y;
        o.z = v[q*4+2] * sc * u.z;
        o.w = v[q*4+3] * sc * u.w;
        z4[q] = o;
    }
}

// ---------------------------------------------------------------------------
extern "C" void kernel_launch(void* const* d_in, const int* in_sizes, int n_in,
                              void* d_out, int out_size, void* d_ws, size_t ws_size,
                              hipStream_t stream) {
    const float* input  = (const float*)d_in[0];   // (2048, 4096) f32
    const int*   Qidxs  = (const int*)d_in[1];     // (4096, 512) i32
    const float* SU     = (const float*)d_in[2];   // (4096,) f32
    const float* SV     = (const float*)d_in[3];   // (4096,) f32
    const float* Wscale = (const float*)d_in[4];   // (1,) f32
    const void*  grid   = (const void*)d_in[9];    // (256, 8) f16 (dtype-probed)

    h16*   W = (h16*)d_ws;                                        // 32 MB
    h16*   Y = (h16*)((char*)d_ws + (size_t)OUTF * GK * 2);       // 16 MB
    float* Z = (float*)d_out;                                     // 32 MB

    hipLaunchKernelGGL(k_decompress, dim3((OUTF * 512) / 256), dim3(256), 0, stream,
                       Qidxs, grid, W);
    hipLaunchKernelGGL(k_fwht_in, dim3(TOKENS), dim3(256), 0, stream,
                       input, SU, Y);
    hipLaunchKernelGGL(k_gemm, dim3((TOKENS / BM) * (OUTF / BN)), dim3(256), 0, stream,
                       Y, W, Z);
    hipLaunchKernelGGL(k_fwht_out, dim3(TOKENS), dim3(256), 0, stream,
                       Z, SV, Wscale);
}

// Round 4
// 141.420 us; speedup vs baseline: 1.1664x; 1.0253x over previous
//
#include <hip/hip_runtime.h>

typedef _Float16 h16;
typedef __attribute__((ext_vector_type(8))) _Float16 f16x8;
typedef __attribute__((ext_vector_type(4))) float f32x4;

#define TOKENS 2048
#define INF    4096   // n_codes * 8
#define OUTF   4096   // m
#define GK     4096

// ---------------------------------------------------------------------------
// Kernel 1: decompress E8P codes -> W (4096 x 4096 fp16, row-major, K-contig)
// ---------------------------------------------------------------------------
__global__ __launch_bounds__(256) void k_decompress(const int* __restrict__ Q,
                                                    const void* __restrict__ gridraw,
                                                    h16* __restrict__ W) {
    __shared__ float gT[8][256];
    __shared__ int   gOdd[256];
    const int tid = threadIdx.x;

    const unsigned short* gu = (const unsigned short*)gridraw;
    const float*          gf = (const float*)gridraw;
    const unsigned short  p0 = gu[0];

    float sum = 0.f;
#pragma unroll
    for (int j = 0; j < 8; ++j) {
        float v;
        if (p0 == 0x3800) {                       // float16
            unsigned short u = gu[tid * 8 + j];
            h16 hv; __builtin_memcpy(&hv, &u, 2);
            v = (float)hv;
        } else if (p0 == 0x3F00) {                // bfloat16
            unsigned int u = ((unsigned int)gu[tid * 8 + j]) << 16;
            __builtin_memcpy(&v, &u, 4);
        } else {                                  // float32
            v = gf[tid * 8 + j];
        }
        gT[j][tid] = v;
        sum += v;
    }
    gOdd[tid] = ((int)(sum + 0.5f)) & 1;
    __syncthreads();

    const int code = blockIdx.x * 256 + tid;
    const int q        = Q[code];
    const int absIdx   = (q >> 8) & 255;
    const int signBits = (q >> 1) & 127;
    const float shift  = (q & 1) ? 0.25f : -0.25f;
    const int neg0 = (__popc(signBits) ^ gOdd[absIdx]) & 1;

    f16x8 o;
    o[0] = (h16)(gT[0][absIdx] * (1.0f - 2.0f * (float)neg0) + shift);
#pragma unroll
    for (int i = 1; i < 8; ++i) {
        float sg = 1.0f - 2.0f * (float)((signBits >> (i - 1)) & 1);
        o[i] = (h16)(gT[i][absIdx] * sg + shift);
    }
    *reinterpret_cast<f16x8*>(W + (size_t)code * 8) = o;
}

// ---------------------------------------------------------------------------
// FWHT-16 fully in registers
// ---------------------------------------------------------------------------
__device__ __forceinline__ void fwht16(float v[16]) {
#pragma unroll
    for (int s = 1; s < 16; s <<= 1)
#pragma unroll
        for (int j = 0; j < 16; ++j)
            if (!(j & s)) {
                float a = v[j], b = v[j + s];
                v[j]     = a + b;
                v[j + s] = a - b;
            }
}

// ---------------------------------------------------------------------------
// Kernel 2: y = fp16( FWHT(x * SU) / 64 )   — radix-16^3
// ---------------------------------------------------------------------------
__global__ __launch_bounds__(256) void k_fwht_in(const float* __restrict__ X,
                                                 const float* __restrict__ SU,
                                                 h16* __restrict__ Y) {
    __shared__ float s[4096 + 256];
    const int row = blockIdx.x, t = threadIdx.x;
    const int hi = t >> 4, lo = t & 15;
    float v[16];
    const float* xr = X + (size_t)row * INF;

#pragma unroll
    for (int j = 0; j < 16; ++j) v[j] = xr[j * 256 + t] * SU[j * 256 + t];
    fwht16(v);
#pragma unroll
    for (int j = 0; j < 16; ++j) s[272 * j + 17 * hi + lo] = v[j];
    __syncthreads();

#pragma unroll
    for (int j = 0; j < 16; ++j) v[j] = s[272 * hi + 17 * j + lo];
    fwht16(v);
#pragma unroll
    for (int j = 0; j < 16; ++j) s[272 * hi + 17 * j + lo] = v[j];
    __syncthreads();

    const int base = 272 * hi + 17 * lo;
#pragma unroll
    for (int j = 0; j < 16; ++j) v[j] = s[base + j];
    fwht16(v);

    f16x8 o0, o1;
#pragma unroll
    for (int j = 0; j < 8; ++j) {
        o0[j] = (h16)(v[j]     * 0.015625f);
        o1[j] = (h16)(v[j + 8] * 0.015625f);
    }
    f16x8* out = reinterpret_cast<f16x8*>(Y + (size_t)row * INF + t * 16);
    out[0] = o0; out[1] = o1;
}

// ---------------------------------------------------------------------------
// Kernel 3: GEMM  z[t][j] = sum_k y[t][k] * W[j][k]  (NT, K-major both)
// 256x256 tile, BK=64, 8 waves (2Mx4N), per-wave 128x64, split-K templated.
// global_load_lds(16B) staging: LINEAR LDS dest, inverse-XOR-swizzled global
// source, XOR-swizzled ds_read (content invariant == verified round-3).
// 4 sub-phases per K-tile (h x kk), raw s_barrier pairs, setprio around MFMA,
// stage issue front-loaded (phases 0/1), single vmcnt(0) at tile boundary.
// ---------------------------------------------------------------------------
#define BM 256
#define BN 256
#define BK 64

template<int KSPLIT>
__global__ __launch_bounds__(512, 1) void k_gemm(const h16* __restrict__ A,
                                                 const h16* __restrict__ B,
                                                 float* __restrict__ C0,
                                                 float* __restrict__ C1) {
    __shared__ __align__(16) h16 lA[2][BM * BK];   // 2 x 32 KiB
    __shared__ __align__(16) h16 lB[2][BN * BK];   // 2 x 32 KiB
    const int tid  = threadIdx.x;
    const int lane = tid & 63;
    const int w    = tid >> 6;          // 0..7
    const int wr   = w >> 2, wc = w & 3;
    const int laneRow = lane & 15, laneK = lane >> 4;

    // bijective XCD swizzle over nwg = 128*KSPLIT (multiple of 8)
    const int nwg = 128 * KSPLIT;
    const int qq  = nwg >> 3;
    const int bid = blockIdx.x;
    const int swz = (bid & 7) * qq + (bid >> 3);
    const int ks  = swz >> 7;           // 0..KSPLIT-1
    const int rem = swz & 127;
    const int mT  = rem >> 4;           // 0..7
    const int nT  = rem & 15;           // 0..15
    const int KT  = (GK / KSPLIT) / BK;
    const int kbase = ks * (GK / KSPLIT);

    float* __restrict__ C = (KSPLIT == 2 && ks == 1) ? C1 : C0;

    // staging: per K-tile 8 gload_lds/thread (4 A + 4 B), 16B each
    size_t aOff[4], bOff[4];
    int ldsOff[4];
#pragma unroll
    for (int j = 0; j < 4; ++j) {
        int ch = j * 512 + tid;           // 0..2047 chunk id
        int rr = ch >> 3, cc = ch & 7;
        int sc = cc ^ (rr & 7);           // inverse-swizzled source col-chunk
        aOff[j] = (size_t)(mT * BM + rr) * GK + (size_t)kbase + sc * 8;
        bOff[j] = (size_t)(nT * BN + rr) * GK + (size_t)kbase + sc * 8;
        ldsOff[j] = (j * 512 + w * 64) * 8;  // wave-uniform linear dest (h16)
    }

    // per-thread LDS read row bases: A rows (h,mi), B rows (nj)
    int aRow[2][4], aX[2][4], bRow[4], bX[4];
#pragma unroll
    for (int h = 0; h < 2; ++h)
#pragma unroll
        for (int mi = 0; mi < 4; ++mi) {
            int r = wr * 128 + h * 64 + mi * 16 + laneRow;
            aRow[h][mi] = r * 8; aX[h][mi] = r & 7;
        }
#pragma unroll
    for (int nj = 0; nj < 4; ++nj) {
        int r = wc * 64 + nj * 16 + laneRow;
        bRow[nj] = r * 8; bX[nj] = r & 7;
    }

    f32x4 acc[2][4][4] = {};

#define STAGE_A(k0, buf) _Pragma("unroll") \
    for (int j = 0; j < 4; ++j) \
        __builtin_amdgcn_global_load_lds( \
            (const __attribute__((address_space(1))) void*)(A + aOff[j] + (k0)), \
            (__attribute__((address_space(3))) void*)(&lA[buf][0] + ldsOff[j]), 16, 0, 0);
#define STAGE_B(k0, buf) _Pragma("unroll") \
    for (int j = 0; j < 4; ++j) \
        __builtin_amdgcn_global_load_lds( \
            (const __attribute__((address_space(1))) void*)(B + bOff[j] + (k0)), \
            (__attribute__((address_space(3))) void*)(&lB[buf][0] + ldsOff[j]), 16, 0, 0);

    // prologue: stage tile 0 -> buf 0, drain, barrier
    STAGE_A(0, 0);
    STAGE_B(0, 0);
    asm volatile("s_waitcnt vmcnt(0)" ::: "memory");
    __builtin_amdgcn_s_barrier();

    int cur = 0;
    for (int t = 0; t < KT; ++t) {
        const h16* pA = &lA[cur][0];
        const h16* pB = &lB[cur][0];
        const int nk0 = (t + 1) * BK;     // next tile k offset
        const bool more = (t + 1) < KT;
        f16x8 bf[4];

        // ---- phase 0: (h=0, kk=0), load B kk0, stage A(t+1) ----
        {
            f16x8 af[4];
#pragma unroll
            for (int nj = 0; nj < 4; ++nj)
                bf[nj] = *reinterpret_cast<const f16x8*>(pB + (bRow[nj] + (laneK ^ bX[nj])) * 8);
#pragma unroll
            for (int mi = 0; mi < 4; ++mi)
                af[mi] = *reinterpret_cast<const f16x8*>(pA + (aRow[0][mi] + (laneK ^ aX[0][mi])) * 8);
            if (more) { STAGE_A(nk0, cur ^ 1); }
            __builtin_amdgcn_s_barrier();
            __builtin_amdgcn_s_setprio(1);
#pragma unroll
            for (int mi = 0; mi < 4; ++mi)
#pragma unroll
                for (int nj = 0; nj < 4; ++nj)
                    acc[0][mi][nj] = __builtin_amdgcn_mfma_f32_16x16x32_f16(
                        af[mi], bf[nj], acc[0][mi][nj], 0, 0, 0);
            __builtin_amdgcn_s_setprio(0);
            __builtin_amdgcn_s_barrier();
        }
        // ---- phase 1: (h=1, kk=0), reuse B, stage B(t+1) ----
        {
            f16x8 af[4];
#pragma unroll
            for (int mi = 0; mi < 4; ++mi)
                af[mi] = *reinterpret_cast<const f16x8*>(pA + (aRow[1][mi] + (laneK ^ aX[1][mi])) * 8);
            if (more) { STAGE_B(nk0, cur ^ 1); }
            __builtin_amdgcn_s_barrier();
            __builtin_amdgcn_s_setprio(1);
#pragma unroll
            for (int mi = 0; mi < 4; ++mi)
#pragma unroll
                for (int nj = 0; nj < 4; ++nj)
                    acc[1][mi][nj] = __builtin_amdgcn_mfma_f32_16x16x32_f16(
                        af[mi], bf[nj], acc[1][mi][nj], 0, 0, 0);
            __builtin_amdgcn_s_setprio(0);
            __builtin_amdgcn_s_barrier();
        }
        // ---- phase 2: (h=0, kk=1), load B kk1 ----
        {
            f16x8 af[4];
#pragma unroll
            for (int nj = 0; nj < 4; ++nj)
                bf[nj] = *reinterpret_cast<const f16x8*>(pB + (bRow[nj] + ((4 + laneK) ^ bX[nj])) * 8);
#pragma unroll
            for (int mi = 0; mi < 4; ++mi)
                af[mi] = *reinterpret_cast<const f16x8*>(pA + (aRow[0][mi] + ((4 + laneK) ^ aX[0][mi])) * 8);
            __builtin_amdgcn_s_barrier();
            __builtin_amdgcn_s_setprio(1);
#pragma unroll
            for (int mi = 0; mi < 4; ++mi)
#pragma unroll
                for (int nj = 0; nj < 4; ++nj)
                    acc[0][mi][nj] = __builtin_amdgcn_mfma_f32_16x16x32_f16(
                        af[mi], bf[nj], acc[0][mi][nj], 0, 0, 0);
            __builtin_amdgcn_s_setprio(0);
            __builtin_amdgcn_s_barrier();
        }
        // ---- phase 3: (h=1, kk=1); boundary: drain stages, barrier ----
        {
            f16x8 af[4];
#pragma unroll
            for (int mi = 0; mi < 4; ++mi)
                af[mi] = *reinterpret_cast<const f16x8*>(pA + (aRow[1][mi] + ((4 + laneK) ^ aX[1][mi])) * 8);
            __builtin_amdgcn_s_barrier();
            __builtin_amdgcn_s_setprio(1);
#pragma unroll
            for (int mi = 0; mi < 4; ++mi)
#pragma unroll
                for (int nj = 0; nj < 4; ++nj)
                    acc[1][mi][nj] = __builtin_amdgcn_mfma_f32_16x16x32_f16(
                        af[mi], bf[nj], acc[1][mi][nj], 0, 0, 0);
            __builtin_amdgcn_s_setprio(0);
            asm volatile("s_waitcnt vmcnt(0)" ::: "memory");  // t+1 stages done
            __builtin_amdgcn_s_barrier();
        }
        cur ^= 1;
    }
#undef STAGE_A
#undef STAGE_B

    // C/D layout: col = lane&15, row = (lane>>4)*4 + reg
    const int col0 = nT * BN + wc * 64 + laneRow;
    const int rowB = mT * BM + wr * 128 + laneK * 4;
#pragma unroll
    for (int h = 0; h < 2; ++h)
#pragma unroll
        for (int mi = 0; mi < 4; ++mi)
#pragma unroll
            for (int nj = 0; nj < 4; ++nj)
#pragma unroll
                for (int rg = 0; rg < 4; ++rg)
                    C[(size_t)(rowB + h * 64 + mi * 16 + rg) * OUTF + col0 + nj * 16]
                        = acc[h][mi][nj][rg];
}

// ---------------------------------------------------------------------------
// Kernel 4: out = FWHT(z0 [+ z1]) * (Wscale/64) * SV — radix-16^3, in-place
// ---------------------------------------------------------------------------
__global__ __launch_bounds__(256) void k_fwht_out(float* __restrict__ Z0,
                                                  const float* __restrict__ Z1,
                                                  int add1,
                                                  const float* __restrict__ SV,
                                                  const float* __restrict__ wscale) {
    __shared__ float s[4096 + 256];
    const int row = blockIdx.x, t = threadIdx.x;
    const int hi = t >> 4, lo = t & 15;
    float v[16];
    float* zr0 = Z0 + (size_t)row * OUTF;
    const float* zr1 = Z1 + (size_t)row * OUTF;

#pragma unroll
    for (int j = 0; j < 16; ++j) v[j] = zr0[j * 256 + t];
    if (add1) {
#pragma unroll
        for (int j = 0; j < 16; ++j) v[j] += zr1[j * 256 + t];
    }
    fwht16(v);
#pragma unroll
    for (int j = 0; j < 16; ++j) s[272 * j + 17 * hi + lo] = v[j];
    __syncthreads();

#pragma unroll
    for (int j = 0; j < 16; ++j) v[j] = s[272 * hi + 17 * j + lo];
    fwht16(v);
#pragma unroll
    for (int j = 0; j < 16; ++j) s[272 * hi + 17 * j + lo] = v[j];
    __syncthreads();

    const int base = 272 * hi + 17 * lo;
#pragma unroll
    for (int j = 0; j < 16; ++j) v[j] = s[base + j];
    fwht16(v);

    const float sc = wscale[0] * 0.015625f;
    const float4* sv4 = reinterpret_cast<const float4*>(SV + t * 16);
    float4* z4 = reinterpret_cast<float4*>(zr0 + t * 16);
#pragma unroll
    for (int q = 0; q < 4; ++q) {
        float4 u = sv4[q];
        float4 o;
        o.x = v[q*4+0] * sc * u.x;
        o.y = v[q*4+1] * sc * u.y;
        o.z = v[q*4+2] * sc * u.z;
        o.w = v[q*4+3] * sc * u.w;
        z4[q] = o;
    }
}

// ---------------------------------------------------------------------------
extern "C" void kernel_launch(void* const* d_in, const int* in_sizes, int n_in,
                              void* d_out, int out_size, void* d_ws, size_t ws_size,
                              hipStream_t stream) {
    const float* input  = (const float*)d_in[0];   // (2048, 4096) f32
    const int*   Qidxs  = (const int*)d_in[1];     // (4096, 512) i32
    const float* SU     = (const float*)d_in[2];   // (4096,) f32
    const float* SV     = (const float*)d_in[3];   // (4096,) f32
    const float* Wscale = (const float*)d_in[4];   // (1,) f32
    const void*  grid   = (const void*)d_in[9];    // (256, 8) grid_abs (dtype-probed)

    h16*   W  = (h16*)d_ws;                                        // 32 MB
    h16*   Y  = (h16*)((char*)d_ws + (size_t)32 * 1024 * 1024);    // 16 MB
    float* Z0 = (float*)d_out;                                     // 32 MB
    float* Z1 = (float*)((char*)d_ws + (size_t)48 * 1024 * 1024);  // 32 MB

    const bool split = ws_size >= (size_t)80 * 1024 * 1024;

    hipLaunchKernelGGL(k_decompress, dim3((OUTF * 512) / 256), dim3(256), 0, stream,
                       Qidxs, grid, W);
    hipLaunchKernelGGL(k_fwht_in, dim3(TOKENS), dim3(256), 0, stream,
                       input, SU, Y);
    if (split) {
        hipLaunchKernelGGL((k_gemm<2>), dim3(256), dim3(512), 0, stream, Y, W, Z0, Z1);
        hipLaunchKernelGGL(k_fwht_out, dim3(TOKENS), dim3(256), 0, stream,
                           Z0, Z1, 1, SV, Wscale);
    } else {
        hipLaunchKernelGGL((k_gemm<1>), dim3(128), dim3(512), 0, stream, Y, W, Z0, Z0);
        hipLaunchKernelGGL(k_fwht_out, dim3(TOKENS), dim3(256), 0, stream,
                           Z0, Z0, 0, SV, Wscale);
    }
}

// Round 5
// 138.276 us; speedup vs baseline: 1.1929x; 1.0227x over previous
//
#include <hip/hip_runtime.h>

typedef short s16;
typedef unsigned short us16;
typedef __attribute__((ext_vector_type(8))) short s16x8;
typedef __attribute__((ext_vector_type(4))) float f32x4;

#define TOKENS 2048
#define INF    4096   // n_codes * 8
#define OUTF   4096   // m
#define GK     4096

// float -> bf16 with round-to-nearest-even
__device__ __forceinline__ us16 f2bf(float f) {
    union { float f; unsigned u; } v; v.f = f;
    unsigned r = v.u + 0x7FFFu + ((v.u >> 16) & 1u);
    return (us16)(r >> 16);
}

// ---------------------------------------------------------------------------
// Kernel 1: decompress E8P codes -> W (4096 x 4096 bf16, row-major, K-contig)
// ---------------------------------------------------------------------------
__global__ __launch_bounds__(256) void k_decompress(const int* __restrict__ Q,
                                                    const void* __restrict__ gridraw,
                                                    us16* __restrict__ W) {
    __shared__ float gT[8][256];
    __shared__ int   gOdd[256];
    const int tid = threadIdx.x;

    const unsigned short* gu = (const unsigned short*)gridraw;
    const float*          gf = (const float*)gridraw;
    const unsigned short  p0 = gu[0];

    float sum = 0.f;
#pragma unroll
    for (int j = 0; j < 8; ++j) {
        float v;
        if (p0 == 0x3800) {                       // float16
            unsigned short u = gu[tid * 8 + j];
            _Float16 hv; __builtin_memcpy(&hv, &u, 2);
            v = (float)hv;
        } else if (p0 == 0x3F00) {                // bfloat16
            unsigned int u = ((unsigned int)gu[tid * 8 + j]) << 16;
            __builtin_memcpy(&v, &u, 4);
        } else {                                  // float32
            v = gf[tid * 8 + j];
        }
        gT[j][tid] = v;
        sum += v;
    }
    gOdd[tid] = ((int)(sum + 0.5f)) & 1;
    __syncthreads();

    const int code = blockIdx.x * 256 + tid;
    const int q        = Q[code];
    const int absIdx   = (q >> 8) & 255;
    const int signBits = (q >> 1) & 127;
    const float shift  = (q & 1) ? 0.25f : -0.25f;
    const int neg0 = (__popc(signBits) ^ gOdd[absIdx]) & 1;

    s16x8 o;
    o[0] = (s16)f2bf(gT[0][absIdx] * (1.0f - 2.0f * (float)neg0) + shift);
#pragma unroll
    for (int i = 1; i < 8; ++i) {
        float sg = 1.0f - 2.0f * (float)((signBits >> (i - 1)) & 1);
        o[i] = (s16)f2bf(gT[i][absIdx] * sg + shift);
    }
    *reinterpret_cast<s16x8*>(W + (size_t)code * 8) = o;
}

// ---------------------------------------------------------------------------
// FWHT-16 fully in registers
// ---------------------------------------------------------------------------
__device__ __forceinline__ void fwht16(float v[16]) {
#pragma unroll
    for (int s = 1; s < 16; s <<= 1)
#pragma unroll
        for (int j = 0; j < 16; ++j)
            if (!(j & s)) {
                float a = v[j], b = v[j + s];
                v[j]     = a + b;
                v[j + s] = a - b;
            }
}

// ---------------------------------------------------------------------------
// Kernel 2: y = bf16( FWHT(x * SU) / 64 )   — radix-16^3
// ---------------------------------------------------------------------------
__global__ __launch_bounds__(256) void k_fwht_in(const float* __restrict__ X,
                                                 const float* __restrict__ SU,
                                                 us16* __restrict__ Y) {
    __shared__ float s[4096 + 256];
    const int row = blockIdx.x, t = threadIdx.x;
    const int hi = t >> 4, lo = t & 15;
    float v[16];
    const float* xr = X + (size_t)row * INF;

#pragma unroll
    for (int j = 0; j < 16; ++j) v[j] = xr[j * 256 + t] * SU[j * 256 + t];
    fwht16(v);
#pragma unroll
    for (int j = 0; j < 16; ++j) s[272 * j + 17 * hi + lo] = v[j];
    __syncthreads();

#pragma unroll
    for (int j = 0; j < 16; ++j) v[j] = s[272 * hi + 17 * j + lo];
    fwht16(v);
#pragma unroll
    for (int j = 0; j < 16; ++j) s[272 * hi + 17 * j + lo] = v[j];
    __syncthreads();

    const int base = 272 * hi + 17 * lo;
#pragma unroll
    for (int j = 0; j < 16; ++j) v[j] = s[base + j];
    fwht16(v);

    s16x8 o0, o1;
#pragma unroll
    for (int j = 0; j < 8; ++j) {
        o0[j] = (s16)f2bf(v[j]     * 0.015625f);
        o1[j] = (s16)f2bf(v[j + 8] * 0.015625f);
    }
    s16x8* out = reinterpret_cast<s16x8*>(Y + (size_t)row * INF + t * 16);
    out[0] = o0; out[1] = o1;
}

// ---------------------------------------------------------------------------
// Kernel 3: GEMM  z[t][j] = sum_k y[t][k] * W[j][k]  (NT, K-major, bf16)
// 256x256 tile, BK=64, 8 waves (2Mx4N), wave tile 128x64, split-K templated.
// mfma_f32_16x16x32_bf16. gload_lds(16B): linear LDS dest, inverse-swizzled
// global source, swizzled ds_read. 4 phases/K-tile (quadrants), raw barriers,
// setprio around MFMA. 2-tiles-ahead prefetch, counted vmcnt(8) boundary.
// ---------------------------------------------------------------------------
#define BM 256
#define BN 256
#define BK 64

template<int KSPLIT>
__global__ __launch_bounds__(512, 1) void k_gemm(const us16* __restrict__ A,
                                                 const us16* __restrict__ B,
                                                 float* __restrict__ C0,
                                                 float* __restrict__ C1) {
    __shared__ __align__(16) us16 lA[2][BM * BK];   // 2 x 32 KiB
    __shared__ __align__(16) us16 lB[2][BN * BK];   // 2 x 32 KiB
    const int tid  = threadIdx.x;
    const int lane = tid & 63;
    const int w    = tid >> 6;          // 0..7
    const int wr   = w >> 2, wc = w & 3;
    const int laneRow = lane & 15, laneK = lane >> 4;

    // bijective XCD swizzle over nwg = 128*KSPLIT (multiple of 8)
    const int nwg = 128 * KSPLIT;
    const int qq  = nwg >> 3;
    const int bid = blockIdx.x;
    const int swz = (bid & 7) * qq + (bid >> 3);
    const int ks  = swz >> 7;
    const int rem = swz & 127;
    const int mT  = rem >> 4;           // 0..7
    const int nT  = rem & 15;           // 0..15
    const int KT  = (GK / KSPLIT) / BK;
    const size_t kbase = (size_t)ks * (GK / KSPLIT);

    float* __restrict__ C = (KSPLIT == 2 && ks == 1) ? C1 : C0;

    // staging: per K-tile 8 gload_lds/thread (4 A + 4 B), 16B each
    size_t aOff[4], bOff[4];
    int ldsOff[4];
#pragma unroll
    for (int j = 0; j < 4; ++j) {
        int ch = j * 512 + tid;           // 0..2047 chunk id
        int rr = ch >> 3, cc = ch & 7;
        int sc = cc ^ (rr & 7);           // inverse-swizzled source col-chunk
        aOff[j] = (size_t)(mT * BM + rr) * GK + kbase + sc * 8;
        bOff[j] = (size_t)(nT * BN + rr) * GK + kbase + sc * 8;
        ldsOff[j] = (j * 512 + w * 64) * 8;  // wave-uniform linear dest
    }

    // LDS read row bases: A rows [mh][mi], B rows [nh][nj]
    int aR[2][4], aXr[2][4];
#pragma unroll
    for (int mh = 0; mh < 2; ++mh)
#pragma unroll
        for (int mi = 0; mi < 4; ++mi) {
            int r = wr * 128 + mh * 64 + mi * 16 + laneRow;
            aR[mh][mi] = r * 8; aXr[mh][mi] = r & 7;
        }
    int bR[2][2], bXr[2][2];
#pragma unroll
    for (int nh = 0; nh < 2; ++nh)
#pragma unroll
        for (int nj = 0; nj < 2; ++nj) {
            int r = wc * 64 + nh * 32 + nj * 16 + laneRow;
            bR[nh][nj] = r * 8; bXr[nh][nj] = r & 7;
        }

    f32x4 acc[2][4][2][2] = {};   // [mh][mi][nh][nj]

#define STAGE(t, buf) do { _Pragma("unroll") \
    for (int j = 0; j < 4; ++j) \
        __builtin_amdgcn_global_load_lds( \
            (const __attribute__((address_space(1))) void*)(A + aOff[j] + (size_t)(t) * BK), \
            (__attribute__((address_space(3))) void*)(&lA[buf][0] + ldsOff[j]), 16, 0, 0); \
    _Pragma("unroll") \
    for (int j = 0; j < 4; ++j) \
        __builtin_amdgcn_global_load_lds( \
            (const __attribute__((address_space(1))) void*)(B + bOff[j] + (size_t)(t) * BK), \
            (__attribute__((address_space(3))) void*)(&lB[buf][0] + ldsOff[j]), 16, 0, 0); \
    } while (0)

    // prologue: stage tiles 0 and 1; wait tile 0 only (counted)
    STAGE(0, 0);
    STAGE(1, 1);
    asm volatile("s_waitcnt vmcnt(8)" ::: "memory");
    __builtin_amdgcn_sched_barrier(0);
    __builtin_amdgcn_s_barrier();

    int cur = 0;
    for (int t = 0; t < KT; ++t) {
        const us16* pA = &lA[cur][0];
        const us16* pB = &lB[cur][0];
        s16x8 af[2][4];      // [kk][mi], current mh
        s16x8 bq[2][2][2];   // [nh][kk][nj]

        // ---- ph0: quadrant (mh0, nh0); reads A(mh0) + B(nh0) ----
#pragma unroll
        for (int kk = 0; kk < 2; ++kk)
#pragma unroll
            for (int mi = 0; mi < 4; ++mi)
                af[kk][mi] = *reinterpret_cast<const s16x8*>(
                    pA + (aR[0][mi] + ((kk * 4 + laneK) ^ aXr[0][mi])) * 8);
#pragma unroll
        for (int kk = 0; kk < 2; ++kk)
#pragma unroll
            for (int nj = 0; nj < 2; ++nj)
                bq[0][kk][nj] = *reinterpret_cast<const s16x8*>(
                    pB + (bR[0][nj] + ((kk * 4 + laneK) ^ bXr[0][nj])) * 8);
        __builtin_amdgcn_s_barrier();
        __builtin_amdgcn_s_setprio(1);
#pragma unroll
        for (int kk = 0; kk < 2; ++kk)
#pragma unroll
            for (int mi = 0; mi < 4; ++mi)
#pragma unroll
                for (int nj = 0; nj < 2; ++nj)
                    acc[0][mi][0][nj] = __builtin_amdgcn_mfma_f32_16x16x32_bf16(
                        af[kk][mi], bq[0][kk][nj], acc[0][mi][0][nj], 0, 0, 0);
        __builtin_amdgcn_s_setprio(0);
        __builtin_amdgcn_s_barrier();

        // ---- ph1: quadrant (mh0, nh1); reads B(nh1) ----
#pragma unroll
        for (int kk = 0; kk < 2; ++kk)
#pragma unroll
            for (int nj = 0; nj < 2; ++nj)
                bq[1][kk][nj] = *reinterpret_cast<const s16x8*>(
                    pB + (bR[1][nj] + ((kk * 4 + laneK) ^ bXr[1][nj])) * 8);
        __builtin_amdgcn_s_barrier();
        __builtin_amdgcn_s_setprio(1);
#pragma unroll
        for (int kk = 0; kk < 2; ++kk)
#pragma unroll
            for (int mi = 0; mi < 4; ++mi)
#pragma unroll
                for (int nj = 0; nj < 2; ++nj)
                    acc[0][mi][1][nj] = __builtin_amdgcn_mfma_f32_16x16x32_bf16(
                        af[kk][mi], bq[1][kk][nj], acc[0][mi][1][nj], 0, 0, 0);
        __builtin_amdgcn_s_setprio(0);
        __builtin_amdgcn_s_barrier();

        // ---- ph2: quadrant (mh1, nh0); reads A(mh1) ----
#pragma unroll
        for (int kk = 0; kk < 2; ++kk)
#pragma unroll
            for (int mi = 0; mi < 4; ++mi)
                af[kk][mi] = *reinterpret_cast<const s16x8*>(
                    pA + (aR[1][mi] + ((kk * 4 + laneK) ^ aXr[1][mi])) * 8);
        __builtin_amdgcn_s_barrier();
        __builtin_amdgcn_s_setprio(1);
#pragma unroll
        for (int kk = 0; kk < 2; ++kk)
#pragma unroll
            for (int mi = 0; mi < 4; ++mi)
#pragma unroll
                for (int nj = 0; nj < 2; ++nj)
                    acc[1][mi][0][nj] = __builtin_amdgcn_mfma_f32_16x16x32_bf16(
                        af[kk][mi], bq[0][kk][nj], acc[1][mi][0][nj], 0, 0, 0);
        __builtin_amdgcn_s_setprio(0);
        __builtin_amdgcn_s_barrier();
        // cur buffer fully read by ALL waves here (last reads drained pre-ph2-MFMA)

        // stage tile t+2 into cur (now-free) buffer
        if (t + 2 < KT) { STAGE(t + 2, cur); }

        // ---- ph3: quadrant (mh1, nh1); register-only ----
        __builtin_amdgcn_s_setprio(1);
#pragma unroll
        for (int kk = 0; kk < 2; ++kk)
#pragma unroll
            for (int mi = 0; mi < 4; ++mi)
#pragma unroll
                for (int nj = 0; nj < 2; ++nj)
                    acc[1][mi][1][nj] = __builtin_amdgcn_mfma_f32_16x16x32_bf16(
                        af[kk][mi], bq[1][kk][nj], acc[1][mi][1][nj], 0, 0, 0);
        __builtin_amdgcn_s_setprio(0);

        // boundary: counted wait — tile t+1's 8 loads retired, t+2's may fly
        if (t + 2 < KT) {
            asm volatile("s_waitcnt vmcnt(8)" ::: "memory");
        } else if (t + 1 < KT) {
            asm volatile("s_waitcnt vmcnt(0)" ::: "memory");
        }
        __builtin_amdgcn_sched_barrier(0);
        if (t + 1 < KT) __builtin_amdgcn_s_barrier();
        cur ^= 1;
    }
#undef STAGE

    // C/D layout: col = lane&15, row = (lane>>4)*4 + reg
    const int colB = nT * BN + wc * 64 + laneRow;
    const int rowB = mT * BM + wr * 128 + laneK * 4;
#pragma unroll
    for (int mh = 0; mh < 2; ++mh)
#pragma unroll
        for (int mi = 0; mi < 4; ++mi)
#pragma unroll
            for (int nh = 0; nh < 2; ++nh)
#pragma unroll
                for (int nj = 0; nj < 2; ++nj)
#pragma unroll
                    for (int rg = 0; rg < 4; ++rg)
                        C[(size_t)(rowB + mh * 64 + mi * 16 + rg) * OUTF
                          + colB + nh * 32 + nj * 16] = acc[mh][mi][nh][nj][rg];
}

// ---------------------------------------------------------------------------
// Kernel 4: out = FWHT(z0 [+ z1]) * (Wscale/64) * SV — radix-16^3, in-place
// ---------------------------------------------------------------------------
__global__ __launch_bounds__(256) void k_fwht_out(float* __restrict__ Z0,
                                                  const float* __restrict__ Z1,
                                                  int add1,
                                                  const float* __restrict__ SV,
                                                  const float* __restrict__ wscale) {
    __shared__ float s[4096 + 256];
    const int row = blockIdx.x, t = threadIdx.x;
    const int hi = t >> 4, lo = t & 15;
    float v[16];
    float* zr0 = Z0 + (size_t)row * OUTF;
    const float* zr1 = Z1 + (size_t)row * OUTF;

#pragma unroll
    for (int j = 0; j < 16; ++j) v[j] = zr0[j * 256 + t];
    if (add1) {
#pragma unroll
        for (int j = 0; j < 16; ++j) v[j] += zr1[j * 256 + t];
    }
    fwht16(v);
#pragma unroll
    for (int j = 0; j < 16; ++j) s[272 * j + 17 * hi + lo] = v[j];
    __syncthreads();

#pragma unroll
    for (int j = 0; j < 16; ++j) v[j] = s[272 * hi + 17 * j + lo];
    fwht16(v);
#pragma unroll
    for (int j = 0; j < 16; ++j) s[272 * hi + 17 * j + lo] = v[j];
    __syncthreads();

    const int base = 272 * hi + 17 * lo;
#pragma unroll
    for (int j = 0; j < 16; ++j) v[j] = s[base + j];
    fwht16(v);

    const float sc = wscale[0] * 0.015625f;
    const float4* sv4 = reinterpret_cast<const float4*>(SV + t * 16);
    float4* z4 = reinterpret_cast<float4*>(zr0 + t * 16);
#pragma unroll
    for (int q = 0; q < 4; ++q) {
        float4 u = sv4[q];
        float4 o;
        o.x = v[q*4+0] * sc * u.x;
        o.y = v[q*4+1] * sc * u.y;
        o.z = v[q*4+2] * sc * u.z;
        o.w = v[q*4+3] * sc * u.w;
        z4[q] = o;
    }
}

// ---------------------------------------------------------------------------
extern "C" void kernel_launch(void* const* d_in, const int* in_sizes, int n_in,
                              void* d_out, int out_size, void* d_ws, size_t ws_size,
                              hipStream_t stream) {
    const float* input  = (const float*)d_in[0];   // (2048, 4096) f32
    const int*   Qidxs  = (const int*)d_in[1];     // (4096, 512) i32
    const float* SU     = (const float*)d_in[2];   // (4096,) f32
    const float* SV     = (const float*)d_in[3];   // (4096,) f32
    const float* Wscale = (const float*)d_in[4];   // (1,) f32
    const void*  grid   = (const void*)d_in[9];    // (256, 8) grid_abs (dtype-probed)

    us16*  W  = (us16*)d_ws;                                       // 32 MB
    us16*  Y  = (us16*)((char*)d_ws + (size_t)32 * 1024 * 1024);   // 16 MB
    float* Z0 = (float*)d_out;                                     // 32 MB
    float* Z1 = (float*)((char*)d_ws + (size_t)48 * 1024 * 1024);  // 32 MB

    const bool split = ws_size >= (size_t)80 * 1024 * 1024;

    hipLaunchKernelGGL(k_decompress, dim3((OUTF * 512) / 256), dim3(256), 0, stream,
                       Qidxs, grid, W);
    hipLaunchKernelGGL(k_fwht_in, dim3(TOKENS), dim3(256), 0, stream,
                       input, SU, Y);
    if (split) {
        hipLaunchKernelGGL((k_gemm<2>), dim3(256), dim3(512), 0, stream, Y, W, Z0, Z1);
        hipLaunchKernelGGL(k_fwht_out, dim3(TOKENS), dim3(256), 0, stream,
                           Z0, Z1, 1, SV, Wscale);
    } else {
        hipLaunchKernelGGL((k_gemm<1>), dim3(128), dim3(512), 0, stream, Y, W, Z0, Z0);
        hipLaunchKernelGGL(k_fwht_out, dim3(TOKENS), dim3(256), 0, stream,
                           Z0, Z0, 0, SV, Wscale);
    }
}

// Round 6
// 132.697 us; speedup vs baseline: 1.2431x; 1.0420x over previous
//
#include <hip/hip_runtime.h>

typedef short s16;
typedef unsigned short us16;
typedef __attribute__((ext_vector_type(8))) short s16x8;
typedef __attribute__((ext_vector_type(4))) float f32x4;

#define TOKENS 2048
#define INF    4096   // n_codes * 8
#define OUTF   4096   // m
#define GK     4096

// float -> bf16 with round-to-nearest-even
__device__ __forceinline__ us16 f2bf(float f) {
    union { float f; unsigned u; } v; v.f = f;
    unsigned r = v.u + 0x7FFFu + ((v.u >> 16) & 1u);
    return (us16)(r >> 16);
}

// ---------------------------------------------------------------------------
// Kernel 1: decompress E8P codes -> W (4096 x 4096 bf16, row-major, K-contig)
// ---------------------------------------------------------------------------
__global__ __launch_bounds__(256) void k_decompress(const int* __restrict__ Q,
                                                    const void* __restrict__ gridraw,
                                                    us16* __restrict__ W) {
    __shared__ float gT[8][256];
    __shared__ int   gOdd[256];
    const int tid = threadIdx.x;

    const unsigned short* gu = (const unsigned short*)gridraw;
    const float*          gf = (const float*)gridraw;
    const unsigned short  p0 = gu[0];

    float sum = 0.f;
#pragma unroll
    for (int j = 0; j < 8; ++j) {
        float v;
        if (p0 == 0x3800) {                       // float16
            unsigned short u = gu[tid * 8 + j];
            _Float16 hv; __builtin_memcpy(&hv, &u, 2);
            v = (float)hv;
        } else if (p0 == 0x3F00) {                // bfloat16
            unsigned int u = ((unsigned int)gu[tid * 8 + j]) << 16;
            __builtin_memcpy(&v, &u, 4);
        } else {                                  // float32
            v = gf[tid * 8 + j];
        }
        gT[j][tid] = v;
        sum += v;
    }
    gOdd[tid] = ((int)(sum + 0.5f)) & 1;
    __syncthreads();

    const int code = blockIdx.x * 256 + tid;
    const int q        = Q[code];
    const int absIdx   = (q >> 8) & 255;
    const int signBits = (q >> 1) & 127;
    const float shift  = (q & 1) ? 0.25f : -0.25f;
    const int neg0 = (__popc(signBits) ^ gOdd[absIdx]) & 1;

    s16x8 o;
    o[0] = (s16)f2bf(gT[0][absIdx] * (1.0f - 2.0f * (float)neg0) + shift);
#pragma unroll
    for (int i = 1; i < 8; ++i) {
        float sg = 1.0f - 2.0f * (float)((signBits >> (i - 1)) & 1);
        o[i] = (s16)f2bf(gT[i][absIdx] * sg + shift);
    }
    *reinterpret_cast<s16x8*>(W + (size_t)code * 8) = o;
}

// ---------------------------------------------------------------------------
// FWHT-16 fully in registers
// ---------------------------------------------------------------------------
__device__ __forceinline__ void fwht16(float v[16]) {
#pragma unroll
    for (int s = 1; s < 16; s <<= 1)
#pragma unroll
        for (int j = 0; j < 16; ++j)
            if (!(j & s)) {
                float a = v[j], b = v[j + s];
                v[j]     = a + b;
                v[j + s] = a - b;
            }
}

// ---------------------------------------------------------------------------
// Kernel 2: y = bf16( FWHT(x * SU) / 64 )   — radix-16^3
// ---------------------------------------------------------------------------
__global__ __launch_bounds__(256) void k_fwht_in(const float* __restrict__ X,
                                                 const float* __restrict__ SU,
                                                 us16* __restrict__ Y) {
    __shared__ float s[4096 + 256];
    const int row = blockIdx.x, t = threadIdx.x;
    const int hi = t >> 4, lo = t & 15;
    float v[16];
    const float* xr = X + (size_t)row * INF;

#pragma unroll
    for (int j = 0; j < 16; ++j) v[j] = xr[j * 256 + t] * SU[j * 256 + t];
    fwht16(v);
#pragma unroll
    for (int j = 0; j < 16; ++j) s[272 * j + 17 * hi + lo] = v[j];
    __syncthreads();

#pragma unroll
    for (int j = 0; j < 16; ++j) v[j] = s[272 * hi + 17 * j + lo];
    fwht16(v);
#pragma unroll
    for (int j = 0; j < 16; ++j) s[272 * hi + 17 * j + lo] = v[j];
    __syncthreads();

    const int base = 272 * hi + 17 * lo;
#pragma unroll
    for (int j = 0; j < 16; ++j) v[j] = s[base + j];
    fwht16(v);

    s16x8 o0, o1;
#pragma unroll
    for (int j = 0; j < 8; ++j) {
        o0[j] = (s16)f2bf(v[j]     * 0.015625f);
        o1[j] = (s16)f2bf(v[j + 8] * 0.015625f);
    }
    s16x8* out = reinterpret_cast<s16x8*>(Y + (size_t)row * INF + t * 16);
    out[0] = o0; out[1] = o1;
}

// ---------------------------------------------------------------------------
// Kernel 3: GEMM  z[t][j] = sum_k y[t][k] * W[j][k]  (NT, K-major, bf16)
// 256x256 tile, BK=64, 8 waves (2Mx4N), wave tile 128x64, split-K templated.
// ONE __syncthreads per K-tile: all 24 ds_reads + 64 MFMA compiler-interleaved
// (fine-grained lgkmcnt), then barrier (implicit vmcnt(0) drains 1-tile-old
// stage loads ~ free), then STAGE(t+2) into the just-freed buffer.
// gload_lds(16B): linear LDS dest, inverse-swizzled global source, swizzled
// ds_read. 2-tiles-ahead prefetch. Bijective XCD swizzle.
// ---------------------------------------------------------------------------
#define BM 256
#define BN 256
#define BK 64

template<int KSPLIT>
__global__ __launch_bounds__(512, 1) void k_gemm(const us16* __restrict__ A,
                                                 const us16* __restrict__ B,
                                                 float* __restrict__ C0,
                                                 float* __restrict__ C1) {
    __shared__ __align__(16) us16 lA[2][BM * BK];   // 2 x 32 KiB
    __shared__ __align__(16) us16 lB[2][BN * BK];   // 2 x 32 KiB
    const int tid  = threadIdx.x;
    const int lane = tid & 63;
    const int w    = tid >> 6;          // 0..7
    const int wr   = w >> 2, wc = w & 3;
    const int laneRow = lane & 15, laneK = lane >> 4;

    // bijective XCD swizzle over nwg = 128*KSPLIT (multiple of 8)
    const int nwg = 128 * KSPLIT;
    const int qq  = nwg >> 3;
    const int bid = blockIdx.x;
    const int swz = (bid & 7) * qq + (bid >> 3);
    const int ks  = swz >> 7;
    const int rem = swz & 127;
    const int mT  = rem >> 4;           // 0..7
    const int nT  = rem & 15;           // 0..15
    const int KT  = (GK / KSPLIT) / BK;
    const size_t kbase = (size_t)ks * (GK / KSPLIT);

    float* __restrict__ C = (KSPLIT == 2 && ks == 1) ? C1 : C0;

    // staging: per K-tile 8 gload_lds/thread (4 A + 4 B), 16B each
    size_t aOff[4], bOff[4];
    int ldsOff[4];
#pragma unroll
    for (int j = 0; j < 4; ++j) {
        int ch = j * 512 + tid;           // 0..2047 chunk id
        int rr = ch >> 3, cc = ch & 7;
        int sc = cc ^ (rr & 7);           // inverse-swizzled source col-chunk
        aOff[j] = (size_t)(mT * BM + rr) * GK + kbase + sc * 8;
        bOff[j] = (size_t)(nT * BN + rr) * GK + kbase + sc * 8;
        ldsOff[j] = (j * 512 + w * 64) * 8;  // wave-uniform linear dest
    }

    // LDS read row bases: A rows [mh][mi], B rows [nh][nj]
    int aR[2][4], aXr[2][4];
#pragma unroll
    for (int mh = 0; mh < 2; ++mh)
#pragma unroll
        for (int mi = 0; mi < 4; ++mi) {
            int r = wr * 128 + mh * 64 + mi * 16 + laneRow;
            aR[mh][mi] = r * 8; aXr[mh][mi] = r & 7;
        }
    int bR[2][2], bXr[2][2];
#pragma unroll
    for (int nh = 0; nh < 2; ++nh)
#pragma unroll
        for (int nj = 0; nj < 2; ++nj) {
            int r = wc * 64 + nh * 32 + nj * 16 + laneRow;
            bR[nh][nj] = r * 8; bXr[nh][nj] = r & 7;
        }

    f32x4 acc[2][4][2][2] = {};   // [mh][mi][nh][nj]

#define STAGE(t, buf) do { _Pragma("unroll") \
    for (int j = 0; j < 4; ++j) \
        __builtin_amdgcn_global_load_lds( \
            (const __attribute__((address_space(1))) void*)(A + aOff[j] + (size_t)(t) * BK), \
            (__attribute__((address_space(3))) void*)(&lA[buf][0] + ldsOff[j]), 16, 0, 0); \
    _Pragma("unroll") \
    for (int j = 0; j < 4; ++j) \
        __builtin_amdgcn_global_load_lds( \
            (const __attribute__((address_space(1))) void*)(B + bOff[j] + (size_t)(t) * BK), \
            (__attribute__((address_space(3))) void*)(&lB[buf][0] + ldsOff[j]), 16, 0, 0); \
    } while (0)

    // prologue: stage tiles 0 and 1 (tile 1's drain cost is absorbed once)
    STAGE(0, 0);
    STAGE(1, 1);
    __syncthreads();

    int cur = 0;
    for (int t = 0; t < KT; ++t) {
        const us16* pA = &lA[cur][0];
        const us16* pB = &lB[cur][0];

        // all B fragments for this K-tile (8 x ds_read_b128)
        s16x8 bf[2][2][2];   // [nh][kk][nj]
#pragma unroll
        for (int nh = 0; nh < 2; ++nh)
#pragma unroll
            for (int kk = 0; kk < 2; ++kk)
#pragma unroll
                for (int nj = 0; nj < 2; ++nj)
                    bf[nh][kk][nj] = *reinterpret_cast<const s16x8*>(
                        pB + (bR[nh][nj] + ((kk * 4 + laneK) ^ bXr[nh][nj])) * 8);

        // two M-halves: 8 A reads + 32 MFMA each; compiler interleaves freely
#pragma unroll
        for (int mh = 0; mh < 2; ++mh) {
            s16x8 af[2][4];  // [kk][mi]
#pragma unroll
            for (int kk = 0; kk < 2; ++kk)
#pragma unroll
                for (int mi = 0; mi < 4; ++mi)
                    af[kk][mi] = *reinterpret_cast<const s16x8*>(
                        pA + (aR[mh][mi] + ((kk * 4 + laneK) ^ aXr[mh][mi])) * 8);
#pragma unroll
            for (int kk = 0; kk < 2; ++kk)
#pragma unroll
                for (int mi = 0; mi < 4; ++mi)
#pragma unroll
                    for (int nh = 0; nh < 2; ++nh)
#pragma unroll
                        for (int nj = 0; nj < 2; ++nj)
                            acc[mh][mi][nh][nj] = __builtin_amdgcn_mfma_f32_16x16x32_bf16(
                                af[kk][mi], bf[nh][kk][nj], acc[mh][mi][nh][nj], 0, 0, 0);
        }

        // one barrier per K-tile: implicit vmcnt(0) drains tile-(t+1) stages
        // (issued a full K-tile ago -> ~free) and fences all waves' LDS reads
        // of buf[cur] before we overwrite it below.
        __syncthreads();

        if (t + 2 < KT) { STAGE(t + 2, cur); }
        cur ^= 1;
    }
#undef STAGE

    // C/D layout: col = lane&15, row = (lane>>4)*4 + reg
    const int colB = nT * BN + wc * 64 + laneRow;
    const int rowB = mT * BM + wr * 128 + laneK * 4;
#pragma unroll
    for (int mh = 0; mh < 2; ++mh)
#pragma unroll
        for (int mi = 0; mi < 4; ++mi)
#pragma unroll
            for (int nh = 0; nh < 2; ++nh)
#pragma unroll
                for (int nj = 0; nj < 2; ++nj)
#pragma unroll
                    for (int rg = 0; rg < 4; ++rg)
                        C[(size_t)(rowB + mh * 64 + mi * 16 + rg) * OUTF
                          + colB + nh * 32 + nj * 16] = acc[mh][mi][nh][nj][rg];
}

// ---------------------------------------------------------------------------
// Kernel 4: out = FWHT(z0 [+ z1]) * (Wscale/64) * SV — radix-16^3, in-place
// ---------------------------------------------------------------------------
__global__ __launch_bounds__(256) void k_fwht_out(float* __restrict__ Z0,
                                                  const float* __restrict__ Z1,
                                                  int add1,
                                                  const float* __restrict__ SV,
                                                  const float* __restrict__ wscale) {
    __shared__ float s[4096 + 256];
    const int row = blockIdx.x, t = threadIdx.x;
    const int hi = t >> 4, lo = t & 15;
    float v[16];
    float* zr0 = Z0 + (size_t)row * OUTF;
    const float* zr1 = Z1 + (size_t)row * OUTF;

#pragma unroll
    for (int j = 0; j < 16; ++j) v[j] = zr0[j * 256 + t];
    if (add1) {
#pragma unroll
        for (int j = 0; j < 16; ++j) v[j] += zr1[j * 256 + t];
    }
    fwht16(v);
#pragma unroll
    for (int j = 0; j < 16; ++j) s[272 * j + 17 * hi + lo] = v[j];
    __syncthreads();

#pragma unroll
    for (int j = 0; j < 16; ++j) v[j] = s[272 * hi + 17 * j + lo];
    fwht16(v);
#pragma unroll
    for (int j = 0; j < 16; ++j) s[272 * hi + 17 * j + lo] = v[j];
    __syncthreads();

    const int base = 272 * hi + 17 * lo;
#pragma unroll
    for (int j = 0; j < 16; ++j) v[j] = s[base + j];
    fwht16(v);

    const float sc = wscale[0] * 0.015625f;
    const float4* sv4 = reinterpret_cast<const float4*>(SV + t * 16);
    float4* z4 = reinterpret_cast<float4*>(zr0 + t * 16);
#pragma unroll
    for (int q = 0; q < 4; ++q) {
        float4 u = sv4[q];
        float4 o;
        o.x = v[q*4+0] * sc * u.x;
        o.y = v[q*4+1] * sc * u.y;
        o.z = v[q*4+2] * sc * u.z;
        o.w = v[q*4+3] * sc * u.w;
        z4[q] = o;
    }
}

// ---------------------------------------------------------------------------
extern "C" void kernel_launch(void* const* d_in, const int* in_sizes, int n_in,
                              void* d_out, int out_size, void* d_ws, size_t ws_size,
                              hipStream_t stream) {
    const float* input  = (const float*)d_in[0];   // (2048, 4096) f32
    const int*   Qidxs  = (const int*)d_in[1];     // (4096, 512) i32
    const float* SU     = (const float*)d_in[2];   // (4096,) f32
    const float* SV     = (const float*)d_in[3];   // (4096,) f32
    const float* Wscale = (const float*)d_in[4];   // (1,) f32
    const void*  grid   = (const void*)d_in[9];    // (256, 8) grid_abs (dtype-probed)

    us16*  W  = (us16*)d_ws;                                       // 32 MB
    us16*  Y  = (us16*)((char*)d_ws + (size_t)32 * 1024 * 1024);   // 16 MB
    float* Z0 = (float*)d_out;                                     // 32 MB
    float* Z1 = (float*)((char*)d_ws + (size_t)48 * 1024 * 1024);  // 32 MB

    const bool split = ws_size >= (size_t)80 * 1024 * 1024;

    hipLaunchKernelGGL(k_decompress, dim3((OUTF * 512) / 256), dim3(256), 0, stream,
                       Qidxs, grid, W);
    hipLaunchKernelGGL(k_fwht_in, dim3(TOKENS), dim3(256), 0, stream,
                       input, SU, Y);
    if (split) {
        hipLaunchKernelGGL((k_gemm<2>), dim3(256), dim3(512), 0, stream, Y, W, Z0, Z1);
        hipLaunchKernelGGL(k_fwht_out, dim3(TOKENS), dim3(256), 0, stream,
                           Z0, Z1, 1, SV, Wscale);
    } else {
        hipLaunchKernelGGL((k_gemm<1>), dim3(128), dim3(512), 0, stream, Y, W, Z0, Z0);
        hipLaunchKernelGGL(k_fwht_out, dim3(TOKENS), dim3(256), 0, stream,
                           Z0, Z0, 0, SV, Wscale);
    }
}

// Round 7
// 130.716 us; speedup vs baseline: 1.2619x; 1.0152x over previous
//
#include <hip/hip_runtime.h>

typedef short s16;
typedef unsigned short us16;
typedef __attribute__((ext_vector_type(8))) short s16x8;
typedef __attribute__((ext_vector_type(4))) float f32x4;

#define TOKENS 2048
#define INF    4096   // n_codes * 8
#define OUTF   4096   // m
#define GK     4096

// float -> bf16 round-to-nearest-even
__device__ __forceinline__ us16 f2bf(float f) {
    union { float f; unsigned u; } v; v.f = f;
    unsigned r = v.u + 0x7FFFu + ((v.u >> 16) & 1u);
    return (us16)(r >> 16);
}

// ---------------------------------------------------------------------------
// FWHT-16 fully in registers
// ---------------------------------------------------------------------------
__device__ __forceinline__ void fwht16(float v[16]) {
#pragma unroll
    for (int s = 1; s < 16; s <<= 1)
#pragma unroll
        for (int j = 0; j < 16; ++j)
            if (!(j & s)) {
                float a = v[j], b = v[j + s];
                v[j]     = a + b;
                v[j + s] = a - b;
            }
}

// ---------------------------------------------------------------------------
// Kernel 1 (merged): blocks [0,2048): y = bf16(FWHT(x*SU)/64)  (radix-16^3)
//                    blocks [2048, 10240): decompress E8P -> W (bf16)
// Independent outputs; merged to overlap on the CU array and save a launch.
// ---------------------------------------------------------------------------
__global__ __launch_bounds__(256) void k_pre(const float* __restrict__ X,
                                             const float* __restrict__ SU,
                                             us16* __restrict__ Y,
                                             const int* __restrict__ Q,
                                             const void* __restrict__ gridraw,
                                             us16* __restrict__ W) {
    __shared__ float s[4096 + 256];
    const int tid = threadIdx.x;

    if (blockIdx.x < TOKENS) {
        // ---------------- FWHT-in ----------------
        const int row = blockIdx.x;
        const int hi = tid >> 4, lo = tid & 15;
        float v[16];
        const float* xr = X + (size_t)row * INF;

#pragma unroll
        for (int j = 0; j < 16; ++j) v[j] = xr[j * 256 + tid] * SU[j * 256 + tid];
        fwht16(v);
#pragma unroll
        for (int j = 0; j < 16; ++j) s[272 * j + 17 * hi + lo] = v[j];
        __syncthreads();

#pragma unroll
        for (int j = 0; j < 16; ++j) v[j] = s[272 * hi + 17 * j + lo];
        fwht16(v);
#pragma unroll
        for (int j = 0; j < 16; ++j) s[272 * hi + 17 * j + lo] = v[j];
        __syncthreads();

        const int base = 272 * hi + 17 * lo;
#pragma unroll
        for (int j = 0; j < 16; ++j) v[j] = s[base + j];
        fwht16(v);

        s16x8 o0, o1;
#pragma unroll
        for (int j = 0; j < 8; ++j) {
            o0[j] = (s16)f2bf(v[j]     * 0.015625f);
            o1[j] = (s16)f2bf(v[j + 8] * 0.015625f);
        }
        s16x8* out = reinterpret_cast<s16x8*>(Y + (size_t)row * INF + tid * 16);
        out[0] = o0; out[1] = o1;
    } else {
        // ---------------- decompress ----------------
        float (*gT)[256] = (float(*)[256])s;          // 8*256 floats
        int* gOdd = (int*)(s + 2048);                 // 256 ints

        const unsigned short* gu = (const unsigned short*)gridraw;
        const float*          gf = (const float*)gridraw;
        const unsigned short  p0 = gu[0];

        float sum = 0.f;
#pragma unroll
        for (int j = 0; j < 8; ++j) {
            float v;
            if (p0 == 0x3800) {                       // float16
                unsigned short u = gu[tid * 8 + j];
                _Float16 hv; __builtin_memcpy(&hv, &u, 2);
                v = (float)hv;
            } else if (p0 == 0x3F00) {                // bfloat16
                unsigned int u = ((unsigned int)gu[tid * 8 + j]) << 16;
                __builtin_memcpy(&v, &u, 4);
            } else {                                  // float32
                v = gf[tid * 8 + j];
            }
            gT[j][tid] = v;
            sum += v;
        }
        gOdd[tid] = ((int)(sum + 0.5f)) & 1;
        __syncthreads();

        const int code = (blockIdx.x - TOKENS) * 256 + tid;
        const int q        = Q[code];
        const int absIdx   = (q >> 8) & 255;
        const int signBits = (q >> 1) & 127;
        const float shift  = (q & 1) ? 0.25f : -0.25f;
        const int neg0 = (__popc(signBits) ^ gOdd[absIdx]) & 1;

        s16x8 o;
        o[0] = (s16)f2bf(gT[0][absIdx] * (1.0f - 2.0f * (float)neg0) + shift);
#pragma unroll
        for (int i = 1; i < 8; ++i) {
            float sg = 1.0f - 2.0f * (float)((signBits >> (i - 1)) & 1);
            o[i] = (s16)f2bf(gT[i][absIdx] * sg + shift);
        }
        *reinterpret_cast<s16x8*>(W + (size_t)code * 8) = o;
    }
}

// ---------------------------------------------------------------------------
// Kernel 2: GEMM  z[t][j] = sum_k y[t][k] * W[j][k]  (NT, K-major, bf16)
// 256x256 tile, BK=64, 8 waves (2Mx4N), wave tile 128x64, split-K=2.
// m201-style 4-phase K-tile: each phase {ds_reads, (stage), s_barrier,
// lgkmcnt(0)+sched_barrier, setprio(1), 16 MFMA, setprio(0), s_barrier}.
// Stages: B(t+2) in ph3, A(t+2) in ph4 (into dbuf[cur], legal: all waves'
// reads of that matrix drained by the preceding lgkmcnt+barrier). Boundary
// vmcnt(8): tile t+1 landed, t+2's 8 loads in flight (counted, never 0).
// ---------------------------------------------------------------------------
#define BM 256
#define BN 256
#define BK 64

template<int KSPLIT>
__global__ __launch_bounds__(512, 1) void k_gemm(const us16* __restrict__ A,
                                                 const us16* __restrict__ B,
                                                 float* __restrict__ C0,
                                                 float* __restrict__ C1) {
    __shared__ __align__(16) us16 lA[2][BM * BK];   // 2 x 32 KiB
    __shared__ __align__(16) us16 lB[2][BN * BK];   // 2 x 32 KiB
    const int tid  = threadIdx.x;
    const int lane = tid & 63;
    const int w    = tid >> 6;          // 0..7
    const int wr   = w >> 2, wc = w & 3;
    const int laneRow = lane & 15, laneK = lane >> 4;

    // bijective XCD swizzle over nwg = 128*KSPLIT (multiple of 8)
    const int nwg = 128 * KSPLIT;
    const int qq  = nwg >> 3;
    const int bid = blockIdx.x;
    const int swz = (bid & 7) * qq + (bid >> 3);
    const int ks  = swz >> 7;
    const int rem = swz & 127;
    const int mT  = rem >> 4;           // 0..7
    const int nT  = rem & 15;           // 0..15
    const int KT  = (GK / KSPLIT) / BK;
    const size_t kbase = (size_t)ks * (GK / KSPLIT);

    float* __restrict__ C = (KSPLIT == 2 && ks == 1) ? C1 : C0;

    // staging: per K-tile 8 gload_lds/thread (4 A + 4 B), 16B each
    size_t aOff[4], bOff[4];
    int ldsOff[4];
#pragma unroll
    for (int j = 0; j < 4; ++j) {
        int ch = j * 512 + tid;           // 0..2047 chunk id
        int rr = ch >> 3, cc = ch & 7;
        int sc = cc ^ (rr & 7);           // inverse-swizzled source col-chunk
        aOff[j] = (size_t)(mT * BM + rr) * GK + kbase + sc * 8;
        bOff[j] = (size_t)(nT * BN + rr) * GK + kbase + sc * 8;
        ldsOff[j] = (j * 512 + w * 64) * 8;  // wave-uniform linear dest
    }

    // LDS read row bases: A rows [mh][mi], B rows [nh][nj]
    int aR[2][4], aXr[2][4];
#pragma unroll
    for (int mh = 0; mh < 2; ++mh)
#pragma unroll
        for (int mi = 0; mi < 4; ++mi) {
            int r = wr * 128 + mh * 64 + mi * 16 + laneRow;
            aR[mh][mi] = r * 8; aXr[mh][mi] = r & 7;
        }
    int bR[2][2], bXr[2][2];
#pragma unroll
    for (int nh = 0; nh < 2; ++nh)
#pragma unroll
        for (int nj = 0; nj < 2; ++nj) {
            int r = wc * 64 + nh * 32 + nj * 16 + laneRow;
            bR[nh][nj] = r * 8; bXr[nh][nj] = r & 7;
        }

    f32x4 acc[2][4][2][2] = {};   // [mh][mi][nh][nj]

#define STAGE_AM(t, buf) do { _Pragma("unroll") \
    for (int j = 0; j < 4; ++j) \
        __builtin_amdgcn_global_load_lds( \
            (const __attribute__((address_space(1))) void*)(A + aOff[j] + (size_t)(t) * BK), \
            (__attribute__((address_space(3))) void*)(&lA[buf][0] + ldsOff[j]), 16, 0, 0); \
    } while (0)
#define STAGE_BM(t, buf) do { _Pragma("unroll") \
    for (int j = 0; j < 4; ++j) \
        __builtin_amdgcn_global_load_lds( \
            (const __attribute__((address_space(1))) void*)(B + bOff[j] + (size_t)(t) * BK), \
            (__attribute__((address_space(3))) void*)(&lB[buf][0] + ldsOff[j]), 16, 0, 0); \
    } while (0)

    // prologue: stage tiles 0,1; wait tile 0 only (counted)
    STAGE_AM(0, 0); STAGE_BM(0, 0);
    STAGE_AM(1, 1); STAGE_BM(1, 1);
    asm volatile("s_waitcnt vmcnt(8)" ::: "memory");
    __builtin_amdgcn_sched_barrier(0);
    __builtin_amdgcn_s_barrier();

    int cur = 0;
    for (int t = 0; t < KT; ++t) {
        const us16* pA = &lA[cur][0];
        const us16* pB = &lB[cur][0];
        s16x8 af[2][4], bf0[2][2], bf1[2][2];

        // ===== ph1: read af(mh0)+bf0; MFMA q(0,0) =====
#pragma unroll
        for (int kk = 0; kk < 2; ++kk)
#pragma unroll
            for (int mi = 0; mi < 4; ++mi)
                af[kk][mi] = *reinterpret_cast<const s16x8*>(
                    pA + (aR[0][mi] + ((kk * 4 + laneK) ^ aXr[0][mi])) * 8);
#pragma unroll
        for (int kk = 0; kk < 2; ++kk)
#pragma unroll
            for (int nj = 0; nj < 2; ++nj)
                bf0[kk][nj] = *reinterpret_cast<const s16x8*>(
                    pB + (bR[0][nj] + ((kk * 4 + laneK) ^ bXr[0][nj])) * 8);
        __builtin_amdgcn_s_barrier();
        asm volatile("s_waitcnt lgkmcnt(0)" ::: "memory");
        __builtin_amdgcn_sched_barrier(0);
        __builtin_amdgcn_s_setprio(1);
#pragma unroll
        for (int kk = 0; kk < 2; ++kk)
#pragma unroll
            for (int mi = 0; mi < 4; ++mi)
#pragma unroll
                for (int nj = 0; nj < 2; ++nj)
                    acc[0][mi][0][nj] = __builtin_amdgcn_mfma_f32_16x16x32_bf16(
                        af[kk][mi], bf0[kk][nj], acc[0][mi][0][nj], 0, 0, 0);
        __builtin_amdgcn_s_setprio(0);
        __builtin_amdgcn_s_barrier();

        // ===== ph2: read bf1; MFMA q(0,1) =====
#pragma unroll
        for (int kk = 0; kk < 2; ++kk)
#pragma unroll
            for (int nj = 0; nj < 2; ++nj)
                bf1[kk][nj] = *reinterpret_cast<const s16x8*>(
                    pB + (bR[1][nj] + ((kk * 4 + laneK) ^ bXr[1][nj])) * 8);
        __builtin_amdgcn_s_barrier();
        asm volatile("s_waitcnt lgkmcnt(0)" ::: "memory");
        __builtin_amdgcn_sched_barrier(0);
        __builtin_amdgcn_s_setprio(1);
#pragma unroll
        for (int kk = 0; kk < 2; ++kk)
#pragma unroll
            for (int mi = 0; mi < 4; ++mi)
#pragma unroll
                for (int nj = 0; nj < 2; ++nj)
                    acc[0][mi][1][nj] = __builtin_amdgcn_mfma_f32_16x16x32_bf16(
                        af[kk][mi], bf1[kk][nj], acc[0][mi][1][nj], 0, 0, 0);
        __builtin_amdgcn_s_setprio(0);
        __builtin_amdgcn_s_barrier();

        // ===== ph3: read af(mh1); stage B(t+2)->lB[cur]; MFMA q(1,0) =====
        // (all waves' B-reads of lB[cur] drained by ph2's lgkmcnt+barrier)
#pragma unroll
        for (int kk = 0; kk < 2; ++kk)
#pragma unroll
            for (int mi = 0; mi < 4; ++mi)
                af[kk][mi] = *reinterpret_cast<const s16x8*>(
                    pA + (aR[1][mi] + ((kk * 4 + laneK) ^ aXr[1][mi])) * 8);
        if (t + 2 < KT) { STAGE_BM(t + 2, cur); }
        __builtin_amdgcn_s_barrier();
        asm volatile("s_waitcnt lgkmcnt(0)" ::: "memory");
        __builtin_amdgcn_sched_barrier(0);
        __builtin_amdgcn_s_setprio(1);
#pragma unroll
        for (int kk = 0; kk < 2; ++kk)
#pragma unroll
            for (int mi = 0; mi < 4; ++mi)
#pragma unroll
                for (int nj = 0; nj < 2; ++nj)
                    acc[1][mi][0][nj] = __builtin_amdgcn_mfma_f32_16x16x32_bf16(
                        af[kk][mi], bf0[kk][nj], acc[1][mi][0][nj], 0, 0, 0);
        __builtin_amdgcn_s_setprio(0);
        __builtin_amdgcn_s_barrier();

        // ===== ph4: stage A(t+2)->lA[cur]; MFMA q(1,1); counted boundary =====
        // (all waves' A-reads of lA[cur] drained by ph3's lgkmcnt+barrier)
        if (t + 2 < KT) { STAGE_AM(t + 2, cur); }
        __builtin_amdgcn_s_barrier();
        __builtin_amdgcn_s_setprio(1);
#pragma unroll
        for (int kk = 0; kk < 2; ++kk)
#pragma unroll
            for (int mi = 0; mi < 4; ++mi)
#pragma unroll
                for (int nj = 0; nj < 2; ++nj)
                    acc[1][mi][1][nj] = __builtin_amdgcn_mfma_f32_16x16x32_bf16(
                        af[kk][mi], bf1[kk][nj], acc[1][mi][1][nj], 0, 0, 0);
        __builtin_amdgcn_s_setprio(0);
        // boundary: t+1's 8 loads retired; t+2's 8 remain in flight
        if (t + 2 < KT) {
            asm volatile("s_waitcnt vmcnt(8)" ::: "memory");
        } else {
            asm volatile("s_waitcnt vmcnt(0)" ::: "memory");
        }
        __builtin_amdgcn_sched_barrier(0);
        if (t + 1 < KT) __builtin_amdgcn_s_barrier();
        cur ^= 1;
    }
#undef STAGE_AM
#undef STAGE_BM

    // C/D layout: col = lane&15, row = (lane>>4)*4 + reg
    const int colB = nT * BN + wc * 64 + laneRow;
    const int rowB = mT * BM + wr * 128 + laneK * 4;
#pragma unroll
    for (int mh = 0; mh < 2; ++mh)
#pragma unroll
        for (int mi = 0; mi < 4; ++mi)
#pragma unroll
            for (int nh = 0; nh < 2; ++nh)
#pragma unroll
                for (int nj = 0; nj < 2; ++nj)
#pragma unroll
                    for (int rg = 0; rg < 4; ++rg)
                        C[(size_t)(rowB + mh * 64 + mi * 16 + rg) * OUTF
                          + colB + nh * 32 + nj * 16] = acc[mh][mi][nh][nj][rg];
}

// ---------------------------------------------------------------------------
// Kernel 3: out = FWHT(z0 [+ z1]) * (Wscale/64) * SV — radix-16^3, in-place
// ---------------------------------------------------------------------------
__global__ __launch_bounds__(256) void k_fwht_out(float* __restrict__ Z0,
                                                  const float* __restrict__ Z1,
                                                  int add1,
                                                  const float* __restrict__ SV,
                                                  const float* __restrict__ wscale) {
    __shared__ float s[4096 + 256];
    const int row = blockIdx.x, t = threadIdx.x;
    const int hi = t >> 4, lo = t & 15;
    float v[16];
    float* zr0 = Z0 + (size_t)row * OUTF;
    const float* zr1 = Z1 + (size_t)row * OUTF;

#pragma unroll
    for (int j = 0; j < 16; ++j) v[j] = zr0[j * 256 + t];
    if (add1) {
#pragma unroll
        for (int j = 0; j < 16; ++j) v[j] += zr1[j * 256 + t];
    }
    fwht16(v);
#pragma unroll
    for (int j = 0; j < 16; ++j) s[272 * j + 17 * hi + lo] = v[j];
    __syncthreads();

#pragma unroll
    for (int j = 0; j < 16; ++j) v[j] = s[272 * hi + 17 * j + lo];
    fwht16(v);
#pragma unroll
    for (int j = 0; j < 16; ++j) s[272 * hi + 17 * j + lo] = v[j];
    __syncthreads();

    const int base = 272 * hi + 17 * lo;
#pragma unroll
    for (int j = 0; j < 16; ++j) v[j] = s[base + j];
    fwht16(v);

    const float sc = wscale[0] * 0.015625f;
    const float4* sv4 = reinterpret_cast<const float4*>(SV + t * 16);
    float4* z4 = reinterpret_cast<float4*>(zr0 + t * 16);
#pragma unroll
    for (int q = 0; q < 4; ++q) {
        float4 u = sv4[q];
        float4 o;
        o.x = v[q*4+0] * sc * u.x;
        o.y = v[q*4+1] * sc * u.y;
        o.z = v[q*4+2] * sc * u.z;
        o.w = v[q*4+3] * sc * u.w;
        z4[q] = o;
    }
}

// ---------------------------------------------------------------------------
extern "C" void kernel_launch(void* const* d_in, const int* in_sizes, int n_in,
                              void* d_out, int out_size, void* d_ws, size_t ws_size,
                              hipStream_t stream) {
    const float* input  = (const float*)d_in[0];   // (2048, 4096) f32
    const int*   Qidxs  = (const int*)d_in[1];     // (4096, 512) i32
    const float* SU     = (const float*)d_in[2];   // (4096,) f32
    const float* SV     = (const float*)d_in[3];   // (4096,) f32
    const float* Wscale = (const float*)d_in[4];   // (1,) f32
    const void*  grid   = (const void*)d_in[9];    // (256, 8) grid_abs (dtype-probed)

    us16*  W  = (us16*)d_ws;                                       // 32 MB
    us16*  Y  = (us16*)((char*)d_ws + (size_t)32 * 1024 * 1024);   // 16 MB
    float* Z0 = (float*)d_out;                                     // 32 MB
    float* Z1 = (float*)((char*)d_ws + (size_t)48 * 1024 * 1024);  // 32 MB

    const bool split = ws_size >= (size_t)80 * 1024 * 1024;

    hipLaunchKernelGGL(k_pre, dim3(TOKENS + (OUTF * 512) / 256), dim3(256), 0, stream,
                       input, SU, Y, Qidxs, grid, W);
    if (split) {
        hipLaunchKernelGGL((k_gemm<2>), dim3(256), dim3(512), 0, stream, Y, W, Z0, Z1);
        hipLaunchKernelGGL(k_fwht_out, dim3(TOKENS), dim3(256), 0, stream,
                           Z0, Z1, 1, SV, Wscale);
    } else {
        hipLaunchKernelGGL((k_gemm<1>), dim3(128), dim3(512), 0, stream, Y, W, Z0, Z0);
        hipLaunchKernelGGL(k_fwht_out, dim3(TOKENS), dim3(256), 0, stream,
                           Z0, Z0, 0, SV, Wscale);
    }
}

// Round 8
// 126.757 us; speedup vs baseline: 1.3014x; 1.0312x over previous
//
#include <hip/hip_runtime.h>

typedef short s16;
typedef unsigned short us16;
typedef __attribute__((ext_vector_type(8))) short s16x8;
typedef __attribute__((ext_vector_type(4))) float f32x4;

#define TOKENS 2048
#define INF    4096   // n_codes * 8
#define OUTF   4096   // m
#define GK     4096

// float -> bf16 round-to-nearest-even
__device__ __forceinline__ us16 f2bf(float f) {
    union { float f; unsigned u; } v; v.f = f;
    unsigned r = v.u + 0x7FFFu + ((v.u >> 16) & 1u);
    return (us16)(r >> 16);
}
__device__ __forceinline__ float bf2f(us16 u) {
    unsigned x = ((unsigned)u) << 16;
    float f; __builtin_memcpy(&f, &x, 4);
    return f;
}

// ---------------------------------------------------------------------------
// FWHT-16 fully in registers
// ---------------------------------------------------------------------------
__device__ __forceinline__ void fwht16(float v[16]) {
#pragma unroll
    for (int s = 1; s < 16; s <<= 1)
#pragma unroll
        for (int j = 0; j < 16; ++j)
            if (!(j & s)) {
                float a = v[j], b = v[j + s];
                v[j]     = a + b;
                v[j + s] = a - b;
            }
}

// ---------------------------------------------------------------------------
// Kernel 1 (merged): blocks [0,2048): y = bf16(FWHT(x*SU)/64)  (radix-16^3)
//                    blocks [2048, 10240): decompress E8P -> W (bf16)
// ---------------------------------------------------------------------------
__global__ __launch_bounds__(256) void k_pre(const float* __restrict__ X,
                                             const float* __restrict__ SU,
                                             us16* __restrict__ Y,
                                             const int* __restrict__ Q,
                                             const void* __restrict__ gridraw,
                                             us16* __restrict__ W) {
    __shared__ float s[4096 + 256];
    const int tid = threadIdx.x;

    if (blockIdx.x < TOKENS) {
        const int row = blockIdx.x;
        const int hi = tid >> 4, lo = tid & 15;
        float v[16];
        const float* xr = X + (size_t)row * INF;

#pragma unroll
        for (int j = 0; j < 16; ++j) v[j] = xr[j * 256 + tid] * SU[j * 256 + tid];
        fwht16(v);
#pragma unroll
        for (int j = 0; j < 16; ++j) s[272 * j + 17 * hi + lo] = v[j];
        __syncthreads();

#pragma unroll
        for (int j = 0; j < 16; ++j) v[j] = s[272 * hi + 17 * j + lo];
        fwht16(v);
#pragma unroll
        for (int j = 0; j < 16; ++j) s[272 * hi + 17 * j + lo] = v[j];
        __syncthreads();

        const int base = 272 * hi + 17 * lo;
#pragma unroll
        for (int j = 0; j < 16; ++j) v[j] = s[base + j];
        fwht16(v);

        s16x8 o0, o1;
#pragma unroll
        for (int j = 0; j < 8; ++j) {
            o0[j] = (s16)f2bf(v[j]     * 0.015625f);
            o1[j] = (s16)f2bf(v[j + 8] * 0.015625f);
        }
        s16x8* out = reinterpret_cast<s16x8*>(Y + (size_t)row * INF + tid * 16);
        out[0] = o0; out[1] = o1;
    } else {
        float (*gT)[256] = (float(*)[256])s;
        int* gOdd = (int*)(s + 2048);

        const unsigned short* gu = (const unsigned short*)gridraw;
        const float*          gf = (const float*)gridraw;
        const unsigned short  p0 = gu[0];

        float sum = 0.f;
#pragma unroll
        for (int j = 0; j < 8; ++j) {
            float v;
            if (p0 == 0x3800) {                       // float16
                unsigned short u = gu[tid * 8 + j];
                _Float16 hv; __builtin_memcpy(&hv, &u, 2);
                v = (float)hv;
            } else if (p0 == 0x3F00) {                // bfloat16
                v = bf2f(gu[tid * 8 + j]);
            } else {                                  // float32
                v = gf[tid * 8 + j];
            }
            gT[j][tid] = v;
            sum += v;
        }
        gOdd[tid] = ((int)(sum + 0.5f)) & 1;
        __syncthreads();

        const int code = (blockIdx.x - TOKENS) * 256 + tid;
        const int q        = Q[code];
        const int absIdx   = (q >> 8) & 255;
        const int signBits = (q >> 1) & 127;
        const float shift  = (q & 1) ? 0.25f : -0.25f;
        const int neg0 = (__popc(signBits) ^ gOdd[absIdx]) & 1;

        s16x8 o;
        o[0] = (s16)f2bf(gT[0][absIdx] * (1.0f - 2.0f * (float)neg0) + shift);
#pragma unroll
        for (int i = 1; i < 8; ++i) {
            float sg = 1.0f - 2.0f * (float)((signBits >> (i - 1)) & 1);
            o[i] = (s16)f2bf(gT[i][absIdx] * sg + shift);
        }
        *reinterpret_cast<s16x8*>(W + (size_t)code * 8) = o;
    }
}

// ---------------------------------------------------------------------------
// Kernel 2: GEMM  z[t][j] = sum_k y[t][k] * W[j][k]  (NT, K-major, bf16)
// 256x256 tile, BK=64, 8 waves (2Mx4N), wave tile 128x64, split-K templated.
// m201-faithful 8-phase / 2-K-tile iteration (t0 in buf0, t1 in buf1):
//   P1 q00(b0)[12 rd]  stage A(t1)h0   P5 q00(b1)[12 rd]  stage A(t0+2)h0
//   P2 q01(b0)[ 4 rd]  stage A(t1)h1   P6 q01(b1)[ 4 rd]  stage A(t0+2)h1
//   P3 q10(b0)[ 8 rd]  stage B(t0+2)h0 P7 q10(b1)[ 8 rd]  stage B(t1+2)h0
//   P4 q11(b0)[ 0 rd]  stage B(t0+2)h1 P8 q11(b1)[ 0 rd]  stage B(t1+2)h1
//        + vmcnt(4) end-P4                  + vmcnt(4) end-P8
// Each stage = one half-tile = 2 gload_lds(16B). Every stage lands >=3 phases
// before first read; vmcnt(4) (loads) retires exactly the 8 loads the next 4
// phases read. Stages write regions past their buffer's last-read barrier.
// Tail: stage tile index clamped to KT-1 (writes only never-read-again bufs,
// keeps vmcnt counts uniform).
// ---------------------------------------------------------------------------
#define BM 256
#define BN 256
#define BK 64

template<int KSPLIT>
__global__ __launch_bounds__(512, 1) void k_gemm(const us16* __restrict__ A,
                                                 const us16* __restrict__ B,
                                                 void* __restrict__ C0v,
                                                 void* __restrict__ C1v) {
    __shared__ __align__(16) us16 lA[2][BM * BK];   // 2 x 32 KiB
    __shared__ __align__(16) us16 lB[2][BN * BK];   // 2 x 32 KiB
    const int tid  = threadIdx.x;
    const int lane = tid & 63;
    const int w    = tid >> 6;          // 0..7
    const int wr   = w >> 2, wc = w & 3;
    const int laneRow = lane & 15, laneK = lane >> 4;

    // bijective XCD swizzle over nwg = 128*KSPLIT (multiple of 8)
    const int nwg = 128 * KSPLIT;
    const int qq  = nwg >> 3;
    const int bid = blockIdx.x;
    const int swz = (bid & 7) * qq + (bid >> 3);
    const int ks  = swz >> 7;
    const int rem = swz & 127;
    const int mT  = rem >> 4;           // 0..7
    const int nT  = rem & 15;           // 0..15
    const int KT  = (GK / KSPLIT) / BK; // 32 (split) / 64 — even
    const size_t kbase = (size_t)ks * (GK / KSPLIT);

    // staging: 8 gload_lds per K-tile (4 A + 4 B), 16B each; j<2 = rows 0..127
    size_t aOff[4], bOff[4];
    int ldsOff[4];
#pragma unroll
    for (int j = 0; j < 4; ++j) {
        int ch = j * 512 + tid;           // 0..2047 chunk id
        int rr = ch >> 3, cc = ch & 7;
        int sc = cc ^ (rr & 7);           // inverse-swizzled source col-chunk
        aOff[j] = (size_t)(mT * BM + rr) * GK + kbase + sc * 8;
        bOff[j] = (size_t)(nT * BN + rr) * GK + kbase + sc * 8;
        ldsOff[j] = (j * 512 + w * 64) * 8;  // wave-uniform linear dest
    }

    int aR[2][4], aXr[2][4];
#pragma unroll
    for (int mh = 0; mh < 2; ++mh)
#pragma unroll
        for (int mi = 0; mi < 4; ++mi) {
            int r = wr * 128 + mh * 64 + mi * 16 + laneRow;
            aR[mh][mi] = r * 8; aXr[mh][mi] = r & 7;
        }
    int bR[2][2], bXr[2][2];
#pragma unroll
    for (int nh = 0; nh < 2; ++nh)
#pragma unroll
        for (int nj = 0; nj < 2; ++nj) {
            int r = wc * 64 + nh * 32 + nj * 16 + laneRow;
            bR[nh][nj] = r * 8; bXr[nh][nj] = r & 7;
        }

    f32x4 acc[2][4][2][2] = {};   // [mh][mi][nh][nj]

#define STG_A(tt, buf, h) do { const size_t _ko = (size_t)((tt) < KT ? (tt) : (KT - 1)) * BK; \
    _Pragma("unroll") \
    for (int j = 2*(h); j < 2*(h) + 2; ++j) \
        __builtin_amdgcn_global_load_lds( \
            (const __attribute__((address_space(1))) void*)(A + aOff[j] + _ko), \
            (__attribute__((address_space(3))) void*)(&lA[buf][0] + ldsOff[j]), 16, 0, 0); \
    } while (0)
#define STG_B(tt, buf, h) do { const size_t _ko = (size_t)((tt) < KT ? (tt) : (KT - 1)) * BK; \
    _Pragma("unroll") \
    for (int j = 2*(h); j < 2*(h) + 2; ++j) \
        __builtin_amdgcn_global_load_lds( \
            (const __attribute__((address_space(1))) void*)(B + bOff[j] + _ko), \
            (__attribute__((address_space(3))) void*)(&lB[buf][0] + ldsOff[j]), 16, 0, 0); \
    } while (0)

#define RD_A(mh, kk, mi, pA) *reinterpret_cast<const s16x8*>( \
        (pA) + (aR[mh][mi] + (((kk) * 4 + laneK) ^ aXr[mh][mi])) * 8)
#define RD_B(nh, kk, nj, pB) *reinterpret_cast<const s16x8*>( \
        (pB) + (bR[nh][nj] + (((kk) * 4 + laneK) ^ bXr[nh][nj])) * 8)

#define MFMA16(mh, nh, BF) _Pragma("unroll") \
    for (int kk = 0; kk < 2; ++kk) _Pragma("unroll") \
        for (int mi = 0; mi < 4; ++mi) _Pragma("unroll") \
            for (int nj = 0; nj < 2; ++nj) \
                acc[mh][mi][nh][nj] = __builtin_amdgcn_mfma_f32_16x16x32_bf16( \
                    af[kk][mi], BF[kk][nj], acc[mh][mi][nh][nj], 0, 0, 0);

    // prologue: issue [B0h0,B0h1,A0h0,A0h1,B1h0,B1h1]; vmcnt(4) retires B0,A0
    STG_B(0, 0, 0); STG_B(0, 0, 1);
    STG_A(0, 0, 0); STG_A(0, 0, 1);
    STG_B(1, 1, 0); STG_B(1, 1, 1);
    asm volatile("s_waitcnt vmcnt(4)" ::: "memory");
    __builtin_amdgcn_sched_barrier(0);
    __builtin_amdgcn_s_barrier();

    const int NITER = KT / 2;
    for (int I = 0; I < NITER; ++I) {
        const int t0 = 2 * I, t1 = 2 * I + 1;
        const us16* pA0 = &lA[0][0];
        const us16* pB0 = &lB[0][0];
        const us16* pA1 = &lA[1][0];
        const us16* pB1 = &lB[1][0];
        s16x8 af[2][4], bf0[2][2], bf1[2][2];

        // ===== P1: q(0,0) buf0 =====
#pragma unroll
        for (int kk = 0; kk < 2; ++kk) {
#pragma unroll
            for (int mi = 0; mi < 4; ++mi) af[kk][mi] = RD_A(0, kk, mi, pA0);
#pragma unroll
            for (int nj = 0; nj < 2; ++nj) bf0[kk][nj] = RD_B(0, kk, nj, pB0);
        }
        STG_A(t1, 1, 0);
        __builtin_amdgcn_s_barrier();
        asm volatile("s_waitcnt lgkmcnt(0)" ::: "memory");
        __builtin_amdgcn_sched_barrier(0);
        __builtin_amdgcn_s_setprio(1);
        MFMA16(0, 0, bf0)
        __builtin_amdgcn_s_setprio(0);
        __builtin_amdgcn_s_barrier();

        // ===== P2: q(0,1) buf0 =====
#pragma unroll
        for (int kk = 0; kk < 2; ++kk)
#pragma unroll
            for (int nj = 0; nj < 2; ++nj) bf1[kk][nj] = RD_B(1, kk, nj, pB0);
        STG_A(t1, 1, 1);
        __builtin_amdgcn_s_barrier();
        asm volatile("s_waitcnt lgkmcnt(0)" ::: "memory");
        __builtin_amdgcn_sched_barrier(0);
        __builtin_amdgcn_s_setprio(1);
        MFMA16(0, 1, bf1)
        __builtin_amdgcn_s_setprio(0);
        __builtin_amdgcn_s_barrier();

        // ===== P3: q(1,0) buf0 =====
#pragma unroll
        for (int kk = 0; kk < 2; ++kk)
#pragma unroll
            for (int mi = 0; mi < 4; ++mi) af[kk][mi] = RD_A(1, kk, mi, pA0);
        STG_B(t0 + 2, 0, 0);
        __builtin_amdgcn_s_barrier();
        asm volatile("s_waitcnt lgkmcnt(0)" ::: "memory");
        __builtin_amdgcn_sched_barrier(0);
        __builtin_amdgcn_s_setprio(1);
        MFMA16(1, 0, bf0)
        __builtin_amdgcn_s_setprio(0);
        __builtin_amdgcn_s_barrier();

        // ===== P4: q(1,1) buf0; vmcnt(4) guards P5-P8 reads =====
        STG_B(t0 + 2, 0, 1);
        __builtin_amdgcn_s_barrier();
        __builtin_amdgcn_s_setprio(1);
        MFMA16(1, 1, bf1)
        __builtin_amdgcn_s_setprio(0);
        asm volatile("s_waitcnt vmcnt(4)" ::: "memory");
        __builtin_amdgcn_sched_barrier(0);
        __builtin_amdgcn_s_barrier();

        // ===== P5: q(0,0) buf1 =====
#pragma unroll
        for (int kk = 0; kk < 2; ++kk) {
#pragma unroll
            for (int mi = 0; mi < 4; ++mi) af[kk][mi] = RD_A(0, kk, mi, pA1);
#pragma unroll
            for (int nj = 0; nj < 2; ++nj) bf0[kk][nj] = RD_B(0, kk, nj, pB1);
        }
        STG_A(t0 + 2, 0, 0);
        __builtin_amdgcn_s_barrier();
        asm volatile("s_waitcnt lgkmcnt(0)" ::: "memory");
        __builtin_amdgcn_sched_barrier(0);
        __builtin_amdgcn_s_setprio(1);
        MFMA16(0, 0, bf0)
        __builtin_amdgcn_s_setprio(0);
        __builtin_amdgcn_s_barrier();

        // ===== P6: q(0,1) buf1 =====
#pragma unroll
        for (int kk = 0; kk < 2; ++kk)
#pragma unroll
            for (int nj = 0; nj < 2; ++nj) bf1[kk][nj] = RD_B(1, kk, nj, pB1);
        STG_A(t0 + 2, 0, 1);
        __builtin_amdgcn_s_barrier();
        asm volatile("s_waitcnt lgkmcnt(0)" ::: "memory");
        __builtin_amdgcn_sched_barrier(0);
        __builtin_amdgcn_s_setprio(1);
        MFMA16(0, 1, bf1)
        __builtin_amdgcn_s_setprio(0);
        __builtin_amdgcn_s_barrier();

        // ===== P7: q(1,0) buf1 =====
#pragma unroll
        for (int kk = 0; kk < 2; ++kk)
#pragma unroll
            for (int mi = 0; mi < 4; ++mi) af[kk][mi] = RD_A(1, kk, mi, pA1);
        STG_B(t1 + 2, 1, 0);
        __builtin_amdgcn_s_barrier();
        asm volatile("s_waitcnt lgkmcnt(0)" ::: "memory");
        __builtin_amdgcn_sched_barrier(0);
        __builtin_amdgcn_s_setprio(1);
        MFMA16(1, 0, bf0)
        __builtin_amdgcn_s_setprio(0);
        __builtin_amdgcn_s_barrier();

        // ===== P8: q(1,1) buf1; vmcnt(4) guards next-iter P1-P4 =====
        STG_B(t1 + 2, 1, 1);
        __builtin_amdgcn_s_barrier();
        __builtin_amdgcn_s_setprio(1);
        MFMA16(1, 1, bf1)
        __builtin_amdgcn_s_setprio(0);
        asm volatile("s_waitcnt vmcnt(4)" ::: "memory");
        __builtin_amdgcn_sched_barrier(0);
        __builtin_amdgcn_s_barrier();
    }
#undef STG_A
#undef STG_B
#undef RD_A
#undef RD_B
#undef MFMA16

    asm volatile("s_waitcnt vmcnt(0)" ::: "memory");

    // C/D layout: col = lane&15, row = (lane>>4)*4 + reg
    const int colB = nT * BN + wc * 64 + laneRow;
    const int rowB = mT * BM + wr * 128 + laneK * 4;
    if constexpr (KSPLIT == 2) {
        us16* C = (ks == 1) ? (us16*)C1v : (us16*)C0v;
#pragma unroll
        for (int mh = 0; mh < 2; ++mh)
#pragma unroll
            for (int mi = 0; mi < 4; ++mi)
#pragma unroll
                for (int nh = 0; nh < 2; ++nh)
#pragma unroll
                    for (int nj = 0; nj < 2; ++nj)
#pragma unroll
                        for (int rg = 0; rg < 4; ++rg)
                            C[(size_t)(rowB + mh * 64 + mi * 16 + rg) * OUTF
                              + colB + nh * 32 + nj * 16] = f2bf(acc[mh][mi][nh][nj][rg]);
    } else {
        float* C = (float*)C0v;
#pragma unroll
        for (int mh = 0; mh < 2; ++mh)
#pragma unroll
            for (int mi = 0; mi < 4; ++mi)
#pragma unroll
                for (int nh = 0; nh < 2; ++nh)
#pragma unroll
                    for (int nj = 0; nj < 2; ++nj)
#pragma unroll
                        for (int rg = 0; rg < 4; ++rg)
                            C[(size_t)(rowB + mh * 64 + mi * 16 + rg) * OUTF
                              + colB + nh * 32 + nj * 16] = acc[mh][mi][nh][nj][rg];
    }
}

// ---------------------------------------------------------------------------
// Kernel 3a: OUT = FWHT(bf16 Z0 + bf16 Z1) * (Wscale/64) * SV   (split path)
// ---------------------------------------------------------------------------
__global__ __launch_bounds__(256) void k_out_split(const us16* __restrict__ Z0,
                                                   const us16* __restrict__ Z1,
                                                   float* __restrict__ OUT,
                                                   const float* __restrict__ SV,
                                                   const float* __restrict__ wscale) {
    __shared__ float s[4096 + 256];
    const int row = blockIdx.x, t = threadIdx.x;
    const int hi = t >> 4, lo = t & 15;
    float v[16];
    const us16* zr0 = Z0 + (size_t)row * OUTF;
    const us16* zr1 = Z1 + (size_t)row * OUTF;

#pragma unroll
    for (int j = 0; j < 16; ++j)
        v[j] = bf2f(zr0[j * 256 + t]) + bf2f(zr1[j * 256 + t]);
    fwht16(v);
#pragma unroll
    for (int j = 0; j < 16; ++j) s[272 * j + 17 * hi + lo] = v[j];
    __syncthreads();

#pragma unroll
    for (int j = 0; j < 16; ++j) v[j] = s[272 * hi + 17 * j + lo];
    fwht16(v);
#pragma unroll
    for (int j = 0; j < 16; ++j) s[272 * hi + 17 * j + lo] = v[j];
    __syncthreads();

    const int base = 272 * hi + 17 * lo;
#pragma unroll
    for (int j = 0; j < 16; ++j) v[j] = s[base + j];
    fwht16(v);

    const float sc = wscale[0] * 0.015625f;
    const float4* sv4 = reinterpret_cast<const float4*>(SV + t * 16);
    float4* o4 = reinterpret_cast<float4*>(OUT + (size_t)row * OUTF + t * 16);
#pragma unroll
    for (int q = 0; q < 4; ++q) {
        float4 u = sv4[q];
        float4 o;
        o.x = v[q*4+0] * sc * u.x;
        o.y = v[q*4+1] * sc * u.y;
        o.z = v[q*4+2] * sc * u.z;
        o.w = v[q*4+3] * sc * u.w;
        o4[q] = o;
    }
}

// ---------------------------------------------------------------------------
// Kernel 3b: fallback, f32 Z in-place on d_out
// ---------------------------------------------------------------------------
__global__ __launch_bounds__(256) void k_out_single(float* __restrict__ Z,
                                                    const float* __restrict__ SV,
                                                    const float* __restrict__ wscale) {
    __shared__ float s[4096 + 256];
    const int row = blockIdx.x, t = threadIdx.x;
    const int hi = t >> 4, lo = t & 15;
    float v[16];
    float* zr = Z + (size_t)row * OUTF;

#pragma unroll
    for (int j = 0; j < 16; ++j) v[j] = zr[j * 256 + t];
    fwht16(v);
#pragma unroll
    for (int j = 0; j < 16; ++j) s[272 * j + 17 * hi + lo] = v[j];
    __syncthreads();

#pragma unroll
    for (int j = 0; j < 16; ++j) v[j] = s[272 * hi + 17 * j + lo];
    fwht16(v);
#pragma unroll
    for (int j = 0; j < 16; ++j) s[272 * hi + 17 * j + lo] = v[j];
    __syncthreads();

    const int base = 272 * hi + 17 * lo;
#pragma unroll
    for (int j = 0; j < 16; ++j) v[j] = s[base + j];
    fwht16(v);

    const float sc = wscale[0] * 0.015625f;
    const float4* sv4 = reinterpret_cast<const float4*>(SV + t * 16);
    float4* z4 = reinterpret_cast<float4*>(zr + t * 16);
#pragma unroll
    for (int q = 0; q < 4; ++q) {
        float4 u = sv4[q];
        float4 o;
        o.x = v[q*4+0] * sc * u.x;
        o.y = v[q*4+1] * sc * u.y;
        o.z = v[q*4+2] * sc * u.z;
        o.w = v[q*4+3] * sc * u.w;
        z4[q] = o;
    }
}

// ---------------------------------------------------------------------------
extern "C" void kernel_launch(void* const* d_in, const int* in_sizes, int n_in,
                              void* d_out, int out_size, void* d_ws, size_t ws_size,
                              hipStream_t stream) {
    const float* input  = (const float*)d_in[0];   // (2048, 4096) f32
    const int*   Qidxs  = (const int*)d_in[1];     // (4096, 512) i32
    const float* SU     = (const float*)d_in[2];   // (4096,) f32
    const float* SV     = (const float*)d_in[3];   // (4096,) f32
    const float* Wscale = (const float*)d_in[4];   // (1,) f32
    const void*  grid   = (const void*)d_in[9];    // (256, 8) grid_abs (dtype-probed)

    us16*  W  = (us16*)d_ws;                                       // 32 MB
    us16*  Y  = (us16*)((char*)d_ws + (size_t)32 * 1024 * 1024);   // 16 MB
    us16*  Z0 = (us16*)((char*)d_ws + (size_t)48 * 1024 * 1024);   // 16 MB (bf16)
    us16*  Z1 = (us16*)((char*)d_ws + (size_t)64 * 1024 * 1024);   // 16 MB (bf16)

    const bool split = ws_size >= (size_t)80 * 1024 * 1024;

    hipLaunchKernelGGL(k_pre, dim3(TOKENS + (OUTF * 512) / 256), dim3(256), 0, stream,
                       input, SU, Y, Qidxs, grid, W);
    if (split) {
        hipLaunchKernelGGL((k_gemm<2>), dim3(256), dim3(512), 0, stream,
                           Y, W, (void*)Z0, (void*)Z1);
        hipLaunchKernelGGL(k_out_split, dim3(TOKENS), dim3(256), 0, stream,
                           Z0, Z1, (float*)d_out, SV, Wscale);
    } else {
        hipLaunchKernelGGL((k_gemm<1>), dim3(128), dim3(512), 0, stream,
                           Y, W, d_out, d_out);
        hipLaunchKernelGGL(k_out_single, dim3(TOKENS), dim3(256), 0, stream,
                           (float*)d_out, SV, Wscale);
    }
}